// Round 2
// baseline (366.470 us; speedup 1.0000x reference)
//
#include <hip/hip_runtime.h>
#include <stdint.h>

#define B_ 2
#define T_ 2048
#define C_ 1024
#define H_ 16
#define DH_ 64
#define M_ (B_*T_)   // 4096

typedef short bhalf8 __attribute__((ext_vector_type(8)));
typedef float floatx4 __attribute__((ext_vector_type(4)));

__device__ __forceinline__ short f2bf(float f) {
  unsigned u = __float_as_uint(f);
  u += 0x7fffu + ((u >> 16) & 1u);   // round-to-nearest-even
  return (short)(u >> 16);
}

// async global->LDS, 16B per lane; lds_dst must be wave-uniform (lane data
// lands at lds_dst + lane*16)
__device__ __forceinline__ void gll16(void* lds_dst, const void* g_src) {
  __builtin_amdgcn_global_load_lds(
      reinterpret_cast<const uint32_t __attribute__((address_space(1)))*>(
          reinterpret_cast<uintptr_t>(g_src)),
      reinterpret_cast<uint32_t __attribute__((address_space(3)))*>(
          reinterpret_cast<uintptr_t>(lds_dst)),
      16, 0, 0);
}

__global__ void cvt_bf16(const float* __restrict__ src, short* __restrict__ dst, int n4) {
  int i = blockIdx.x * blockDim.x + threadIdx.x;
  if (i >= n4) return;
  float4 v = ((const float4*)src)[i];
  short4 o;
  o.x = f2bf(v.x); o.y = f2bf(v.y); o.z = f2bf(v.z); o.w = f2bf(v.w);
  ((short4*)dst)[i] = o;
}

// C = A(M x K) @ B^T where B is (N x K), both bf16 row-major, K = 1024.
// MODE 0: fp32 out, row-major (M x C_)          [final Wo projection]
// MODE 2: bf16 out, (B,H,T,DH) + RoPE           [Q, K]
// MODE 3: bf16 out, (B,H,DH,T) "transposed"     [V^T: A=Wv (1024xC), B=X (4096xC)]
template<int MODE>
__global__ __launch_bounds__(256) void gemm_bt(
    const short* __restrict__ A, const short* __restrict__ Bm,
    void* __restrict__ Cout)
{
  __shared__ __align__(16) short As[128*32];
  __shared__ __align__(16) short Bs[128*32];
  const int tid  = threadIdx.x;
  const int lane = tid & 63;
  const int wv   = tid >> 6;
  const int l15  = lane & 15;
  const int quad = lane >> 4;
  const int wm   = (wv >> 1) << 6;   // wave row offset (2x2 wave grid)
  const int wn   = (wv & 1) << 6;    // wave col offset (= one head for MODE 2)
  const int n0   = blockIdx.x << 7;
  const int m0   = blockIdx.y << 7;
  const int K    = C_;

  floatx4 acc[4][4] = {};

  const short* Ab = A  + (size_t)m0 * K;
  const short* Bb = Bm + (size_t)n0 * K;

  for (int k0 = 0; k0 < K; k0 += 32) {
    __syncthreads();                     // LDS reuse guard
#pragma unroll
    for (int i = 0; i < 2; ++i) {
      int c = i*256 + tid;               // 512 chunks of 16B per tile
      int row = c >> 2, off = (c & 3) * 8;
      gll16(&As[(i*256 + (wv<<6))*8], Ab + (size_t)row*K + k0 + off);
      gll16(&Bs[(i*256 + (wv<<6))*8], Bb + (size_t)row*K + k0 + off);
    }
    __syncthreads();
    bhalf8 af[4], bfr[4];
#pragma unroll
    for (int rt = 0; rt < 4; ++rt)
      af[rt] = *(const bhalf8*)&As[(wm + rt*16 + l15)*32 + quad*8];
#pragma unroll
    for (int ct = 0; ct < 4; ++ct)
      bfr[ct] = *(const bhalf8*)&Bs[(wn + ct*16 + l15)*32 + quad*8];
#pragma unroll
    for (int rt = 0; rt < 4; ++rt)
#pragma unroll
      for (int ct = 0; ct < 4; ++ct)
        acc[rt][ct] = __builtin_amdgcn_mfma_f32_16x16x32_bf16(af[rt], bfr[ct], acc[rt][ct], 0, 0, 0);
  }

  if (MODE == 0) {
    float* Cf = (float*)Cout;
#pragma unroll
    for (int rt = 0; rt < 4; ++rt)
#pragma unroll
      for (int r = 0; r < 4; ++r) {
        int n = m0 + wm + rt*16 + quad*4 + r;
#pragma unroll
        for (int ct = 0; ct < 4; ++ct)
          Cf[(size_t)n * C_ + n0 + wn + ct*16 + l15] = acc[rt][ct][r];
      }
  } else if (MODE == 3) {
    short* Cb = (short*)Cout;
#pragma unroll
    for (int rt = 0; rt < 4; ++rt)
#pragma unroll
      for (int r = 0; r < 4; ++r) {
        int o = m0 + wm + rt*16 + quad*4 + r;      // channel = h*64+d
#pragma unroll
        for (int ct = 0; ct < 4; ++ct) {
          int n  = n0 + wn + ct*16 + l15;          // token index (b,t)
          int bb = n >> 11, t = n & (T_-1);
          Cb[(size_t)bb*(C_*T_) + (size_t)o*T_ + t] = f2bf(acc[rt][ct][r]);
        }
      }
  } else {
    short* Cb = (short*)Cout;
#pragma unroll
    for (int rt = 0; rt < 4; ++rt)
#pragma unroll
      for (int r = 0; r < 4; ++r) {
        int n  = m0 + wm + rt*16 + quad*4 + r;
        int bb = n >> 11, t = n & (T_-1);
        int hh = (n0 + wn) >> 6;                   // wave covers exactly one head
        size_t base = ((size_t)(bb*H_ + hh)*T_ + t)*DH_;
        float tf = (float)t;
#pragma unroll
        for (int ct = 0; ct < 2; ++ct) {
          int ii = ct*16 + l15;                    // freq index 0..31
          float ang = tf * exp2f((float)ii * (-0.4152410118609203f));
          float sn = __sinf(ang), cs = __cosf(ang);
          float xlo = acc[rt][ct][r], xhi = acc[rt][ct+2][r];
          Cb[base + ii]      = f2bf(xlo*cs - xhi*sn);
          Cb[base + ii + 32] = f2bf(xhi*cs + xlo*sn);
        }
      }
  }
}

// One block per (b, h, 128 query rows). Causal decay retention + fused GroupNorm.
// LDS 32KB -> 4 blocks/CU (16 waves/CU). Q fragments live in registers.
__global__ __launch_bounds__(256, 4) void retention(
    const short* __restrict__ Qb, const short* __restrict__ Kb, const short* __restrict__ Vt,
    const float* __restrict__ gnw, const float* __restrict__ gnb,
    short* __restrict__ Xn)
{
  __shared__ __align__(16) short Ks[64*64];    // XOR-swizzled: granule g at g^(row&7)
  __shared__ __align__(16) short Vs[64*64];    // V^T tile [d][s], same swizzle
  __shared__ __align__(16) short Ss[128*64];   // swizzle (row>>1)&7

  const int tid = threadIdx.x, lane = tid & 63, wv = tid >> 6;
  const int l15 = lane & 15, quad = lane >> 4;

  // XCD-clustering swizzle: all 16 q-blocks of one (b,h) share blockIdx%8
  const int flat = blockIdx.x;
  const int p  = (flat & 7) | (((flat >> 7) & 3) << 3);   // (b,h) pair 0..31
  const int qi = (flat >> 3) & 15;
  const int b = p >> 4, h = p & 15;
  const int n0 = qi << 7;

  const float log2g = log2f(1.f - exp2f(-5.f - (float)h));

  const short* Qg  = Qb + ((size_t)(b*H_ + h)*T_ + n0 + (wv<<5)) * DH_;
  const short* Kg  = Kb + ((size_t)(b*H_ + h)*T_) * DH_;
  const short* Vtg = Vt + (size_t)b*(C_*T_) + (size_t)h*DH_*T_;

  // Q fragments for the wave's 32 rows, kept in registers all loop long
  bhalf8 aq[2][2];
#pragma unroll
  for (int rt = 0; rt < 2; ++rt)
#pragma unroll
    for (int ks = 0; ks < 2; ++ks)
      aq[rt][ks] = *(const bhalf8*)(Qg + (rt*16 + l15)*DH_ + ks*32 + quad*8);

  // decay factors: gamma^(n-m)/8 = rowf(n) * colf0(m)*tilef
  float rowf[2][4], colf0[4];
#pragma unroll
  for (int rt = 0; rt < 2; ++rt)
#pragma unroll
    for (int r = 0; r < 4; ++r)
      rowf[rt][r] = exp2f(log2g * (float)((wv<<5) + rt*16 + (quad<<2) + r)) * 0.125f;
#pragma unroll
  for (int ct = 0; ct < 4; ++ct)
    colf0[ct] = exp2f(-log2g * (float)(ct*16 + l15));

  floatx4 oacc[2][4] = {};
  const int mtmax = (n0 >> 6) + 1;
  for (int mt = 0; mt <= mtmax; ++mt) {
    const int m0 = mt << 6;
    if (log2g * (float)(n0 - m0 - 63) < -34.f) continue;  // fully-decayed tile

    __syncthreads();                         // prev-tile reads done
#pragma unroll
    for (int i = 0; i < 2; ++i) {
      int slot = (i<<8) + tid;
      int r = slot >> 3, g = (slot & 7) ^ (r & 7);
      gll16(&Ks[((i<<8) + (wv<<6))*8], Kg  + (size_t)(m0 + r)*DH_ + (g<<3));
      gll16(&Vs[((i<<8) + (wv<<6))*8], Vtg + (size_t)r*T_ + m0 + (g<<3));
    }
    __syncthreads();                         // staged (vmcnt drain at barrier)

    if (m0 <= n0 + (wv<<5) + 31) {           // wave has any unmasked rows
      floatx4 sacc[2][4] = {};
#pragma unroll
      for (int ks = 0; ks < 2; ++ks) {
        bhalf8 bk[4];
#pragma unroll
        for (int ct = 0; ct < 4; ++ct) {
          int row = ct*16 + l15;
          bk[ct] = *(const bhalf8*)&Ks[(row<<6) + ((((ks<<2)+quad) ^ (row&7))<<3)];
        }
#pragma unroll
        for (int rt = 0; rt < 2; ++rt)
#pragma unroll
          for (int ct = 0; ct < 4; ++ct)
            sacc[rt][ct] = __builtin_amdgcn_mfma_f32_16x16x32_bf16(aq[rt][ks], bk[ct], sacc[rt][ct], 0, 0, 0);
      }

      const float tilef = exp2f(log2g * (float)(n0 - m0));
      const bool maskT = (m0 + 64 > n0);
#pragma unroll
      for (int rt = 0; rt < 2; ++rt)
#pragma unroll
        for (int ct = 0; ct < 4; ++ct) {
          float cf = colf0[ct] * tilef;
          int colg = (ct<<1) + (l15>>3);
#pragma unroll
          for (int r = 0; r < 4; ++r) {
            int row = (wv<<5) + rt*16 + (quad<<2) + r;
            float v = sacc[rt][ct][r] * (rowf[rt][r] * cf);
            if (maskT && (n0 + row) < (m0 + ct*16 + l15)) v = 0.f;
            Ss[(row<<6) + ((colg ^ ((row>>1)&7))<<3) + (l15&7)] = f2bf(v);
          }
        }
      // no barrier: wave reads back only its own Ss rows (lgkmcnt ordering)

#pragma unroll
      for (int ks = 0; ks < 2; ++ks) {
        bhalf8 as_[2], bv[4];
#pragma unroll
        for (int rt = 0; rt < 2; ++rt) {
          int row = (wv<<5) + rt*16 + l15;
          as_[rt] = *(const bhalf8*)&Ss[(row<<6) + ((((ks<<2)+quad) ^ ((row>>1)&7))<<3)];
        }
#pragma unroll
        for (int ct = 0; ct < 4; ++ct) {
          int row = ct*16 + l15;
          bv[ct] = *(const bhalf8*)&Vs[(row<<6) + ((((ks<<2)+quad) ^ (row&7))<<3)];
        }
#pragma unroll
        for (int rt = 0; rt < 2; ++rt)
#pragma unroll
          for (int ct = 0; ct < 4; ++ct)
            oacc[rt][ct] = __builtin_amdgcn_mfma_f32_16x16x32_bf16(as_[rt], bv[ct], oacc[rt][ct], 0, 0, 0);
      }
    }
  }

  // fused GroupNorm over DH, write (B,T,C) bf16
#pragma unroll
  for (int rt = 0; rt < 2; ++rt)
#pragma unroll
    for (int r = 0; r < 4; ++r) {
      float s1 = oacc[rt][0][r] + oacc[rt][1][r] + oacc[rt][2][r] + oacc[rt][3][r];
      float s2 = oacc[rt][0][r]*oacc[rt][0][r] + oacc[rt][1][r]*oacc[rt][1][r]
               + oacc[rt][2][r]*oacc[rt][2][r] + oacc[rt][3][r]*oacc[rt][3][r];
#pragma unroll
      for (int off = 1; off < 16; off <<= 1) {
        s1 += __shfl_xor(s1, off);
        s2 += __shfl_xor(s2, off);
      }
      float mean = s1 * (1.f/64.f);
      float var  = s2 * (1.f/64.f) - mean*mean;
      float rstd = rsqrtf(var + 1e-5f);
      int t = n0 + (wv<<5) + rt*16 + (quad<<2) + r;
      size_t obase = ((size_t)b*T_ + t)*C_ + h*DH_;
#pragma unroll
      for (int ct = 0; ct < 4; ++ct) {
        int d = ct*16 + l15;
        float y = (oacc[rt][ct][r] - mean)*rstd*gnw[h*DH_ + d] + gnb[h*DH_ + d];
        Xn[obase + d] = f2bf(y);
      }
    }
}

extern "C" void kernel_launch(void* const* d_in, const int* in_sizes, int n_in,
                              void* d_out, int out_size, void* d_ws, size_t ws_size,
                              hipStream_t stream) {
  (void)in_sizes; (void)n_in; (void)out_size; (void)ws_size;
  const float* x   = (const float*)d_in[0];
  const float* Wq  = (const float*)d_in[1];
  const float* Wk  = (const float*)d_in[2];
  const float* Wv  = (const float*)d_in[3];
  const float* Wo  = (const float*)d_in[4];
  const float* gnw = (const float*)d_in[5];
  const float* gnb = (const float*)d_in[6];
  float* out = (float*)d_out;

  char* ws = (char*)d_ws;                 // 48 MB used
  short* Xb  = (short*)(ws);              // x bf16:  4096x1024 (8 MB)
  short* Wqb = (short*)(ws + (8u<<20));   // 2 MB each
  short* Wkb = (short*)(ws + (10u<<20));
  short* Wvb = (short*)(ws + (12u<<20));
  short* Wob = (short*)(ws + (14u<<20));
  short* Qb  = (short*)(ws + (16u<<20));  // (B,H,T,DH) bf16, 8 MB each
  short* Kb  = (short*)(ws + (24u<<20));
  short* Vtw = (short*)(ws + (32u<<20));  // V^T (B,H,DH,T) bf16
  short* Xn  = (short*)(ws + (40u<<20));  // normalized retention out (B,T,C) bf16

  cvt_bf16<<<(M_*C_/4 + 255)/256, 256, 0, stream>>>(x,  Xb,  M_*C_/4);
  cvt_bf16<<<(C_*C_/4 + 255)/256, 256, 0, stream>>>(Wq, Wqb, C_*C_/4);
  cvt_bf16<<<(C_*C_/4 + 255)/256, 256, 0, stream>>>(Wk, Wkb, C_*C_/4);
  cvt_bf16<<<(C_*C_/4 + 255)/256, 256, 0, stream>>>(Wv, Wvb, C_*C_/4);
  cvt_bf16<<<(C_*C_/4 + 255)/256, 256, 0, stream>>>(Wo, Wob, C_*C_/4);

  dim3 gg(C_/128, M_/128);
  gemm_bt<2><<<gg, 256, 0, stream>>>(Xb, Wqb, Qb);           // Q with RoPE
  gemm_bt<2><<<gg, 256, 0, stream>>>(Xb, Wkb, Kb);           // K with RoPE
  gemm_bt<3><<<dim3(M_/128, C_/128), 256, 0, stream>>>(Wvb, Xb, Vtw);  // V^T
  retention<<<512, 256, 0, stream>>>(Qb, Kb, Vtw, gnw, gnb, Xn);
  gemm_bt<0><<<gg, 256, 0, stream>>>(Xn, Wob, (void*)out);
}

// Round 3
// 216.066 us; speedup vs baseline: 1.6961x; 1.6961x over previous
//
#include <hip/hip_runtime.h>
#include <stdint.h>

#define B_ 2
#define T_ 2048
#define C_ 1024
#define H_ 16
#define DH_ 64
#define M_ (B_*T_)   // 4096

typedef short bhalf8 __attribute__((ext_vector_type(8)));
typedef float floatx4 __attribute__((ext_vector_type(4)));

__device__ __forceinline__ short f2bf(float f) {
  unsigned u = __float_as_uint(f);
  u += 0x7fffu + ((u >> 16) & 1u);   // round-to-nearest-even
  return (short)(u >> 16);
}

// async global->LDS, 16B per lane; lds_dst must be wave-uniform (lane data
// lands at lds_dst + lane*16)
__device__ __forceinline__ void gll16(void* lds_dst, const void* g_src) {
  __builtin_amdgcn_global_load_lds(
      reinterpret_cast<const uint32_t __attribute__((address_space(1)))*>(
          reinterpret_cast<uintptr_t>(g_src)),
      reinterpret_cast<uint32_t __attribute__((address_space(3)))*>(
          reinterpret_cast<uintptr_t>(lds_dst)),
      16, 0, 0);
}

__global__ void cvt_bf16(const float* __restrict__ src, short* __restrict__ dst, int n4) {
  int i = blockIdx.x * blockDim.x + threadIdx.x;
  if (i >= n4) return;
  float4 v = ((const float4*)src)[i];
  short4 o;
  o.x = f2bf(v.x); o.y = f2bf(v.y); o.z = f2bf(v.z); o.w = f2bf(v.w);
  ((short4*)dst)[i] = o;
}

// Fused Q/K/V projection. Grid (24, 32): x<8 -> Q-tile, x<16 -> K-tile,
// x>=16 -> V-tile (operands swapped so C/D layout gives coalesced V^T store).
// 768 blocks = 3/CU.
__global__ __launch_bounds__(256) void gemm_qkv(
    const short* __restrict__ X,
    const short* __restrict__ Wq, const short* __restrict__ Wk, const short* __restrict__ Wv,
    short* __restrict__ Qb, short* __restrict__ Kb, short* __restrict__ Vt)
{
  __shared__ __align__(16) short As[128*32];
  __shared__ __align__(16) short Bs[128*32];
  const int tid  = threadIdx.x;
  const int lane = tid & 63;
  const int wv   = tid >> 6;
  const int l15  = lane & 15;
  const int quad = lane >> 4;
  const int wm   = (wv >> 1) << 6;   // wave row offset (2x2 wave grid)
  const int wn   = (wv & 1) << 6;    // wave col offset
  const int nx   = blockIdx.x;
  const int m0   = blockIdx.y << 7;
  const int K    = C_;

  const short *Ab, *Bb;
  int nloc, kind;                    // 0=Q 1=K 2=V
  if (nx < 8)       { kind = 0; nloc = nx << 7;        Ab = X  + (size_t)m0*K;   Bb = Wq + (size_t)nloc*K; }
  else if (nx < 16) { kind = 1; nloc = (nx - 8) << 7;  Ab = X  + (size_t)m0*K;   Bb = Wk + (size_t)nloc*K; }
  else              { kind = 2; nloc = (nx - 16) << 7; Ab = Wv + (size_t)nloc*K; Bb = X  + (size_t)m0*K;   }

  floatx4 acc[4][4] = {};

  for (int k0 = 0; k0 < K; k0 += 32) {
    __syncthreads();                     // LDS reuse guard
#pragma unroll
    for (int i = 0; i < 2; ++i) {
      int c = i*256 + tid;               // 512 chunks of 16B per tile
      int row = c >> 2, off = (c & 3) * 8;
      gll16(&As[(i*256 + (wv<<6))*8], Ab + (size_t)row*K + k0 + off);
      gll16(&Bs[(i*256 + (wv<<6))*8], Bb + (size_t)row*K + k0 + off);
    }
    __syncthreads();                     // vmcnt drain at barrier
    bhalf8 af[4], bfr[4];
#pragma unroll
    for (int rt = 0; rt < 4; ++rt)
      af[rt] = *(const bhalf8*)&As[(wm + rt*16 + l15)*32 + quad*8];
#pragma unroll
    for (int ct = 0; ct < 4; ++ct)
      bfr[ct] = *(const bhalf8*)&Bs[(wn + ct*16 + l15)*32 + quad*8];
#pragma unroll
    for (int rt = 0; rt < 4; ++rt)
#pragma unroll
      for (int ct = 0; ct < 4; ++ct)
        acc[rt][ct] = __builtin_amdgcn_mfma_f32_16x16x32_bf16(af[rt], bfr[ct], acc[rt][ct], 0, 0, 0);
  }

  if (kind < 2) {                        // Q or K: RoPE epilogue -> (B,H,T,DH)
    short* Cb = kind ? Kb : Qb;
    const int hh = (nloc + wn) >> 6;     // wave covers exactly one head
#pragma unroll
    for (int rt = 0; rt < 4; ++rt)
#pragma unroll
      for (int r = 0; r < 4; ++r) {
        int n  = m0 + wm + rt*16 + quad*4 + r;
        int bb = n >> 11, t = n & (T_-1);
        size_t base = ((size_t)(bb*H_ + hh)*T_ + t)*DH_;
        float tf = (float)t;
#pragma unroll
        for (int ct = 0; ct < 2; ++ct) {
          int ii = ct*16 + l15;          // freq index 0..31
          float ang = tf * exp2f((float)ii * (-0.4152410118609203f));
          float sn = __sinf(ang), cs = __cosf(ang);
          float xlo = acc[rt][ct][r], xhi = acc[rt][ct+2][r];
          Cb[base + ii]      = f2bf(xlo*cs - xhi*sn);
          Cb[base + ii + 32] = f2bf(xhi*cs + xlo*sn);
        }
      }
  } else {                               // V: rows=channels, cols=tokens -> V^T store
#pragma unroll
    for (int rt = 0; rt < 4; ++rt)
#pragma unroll
      for (int r = 0; r < 4; ++r) {
        int o = nloc + wm + rt*16 + quad*4 + r;   // channel
#pragma unroll
        for (int ct = 0; ct < 4; ++ct) {
          int n  = m0 + wn + ct*16 + l15;         // token
          int bb = n >> 11, t = n & (T_-1);
          Vt[(size_t)bb*(C_*T_) + (size_t)o*T_ + t] = f2bf(acc[rt][ct][r]);
        }
      }
  }
}

// Final projection: C = Xn(4096 x 1024) @ Wo^T, fp32 out.
// M-tile 128, N-tile 64, BK 64, XOR-swizzled LDS. 512 blocks = 2/CU.
__global__ __launch_bounds__(256) void gemm_out(
    const short* __restrict__ A, const short* __restrict__ Bm, float* __restrict__ Cf)
{
  __shared__ __align__(16) short As[128*64];
  __shared__ __align__(16) short Bs[64*64];
  const int tid = threadIdx.x, lane = tid & 63, wv = tid >> 6;
  const int l15 = lane & 15, quad = lane >> 4;
  const int n0 = blockIdx.x << 6;
  const int m0 = blockIdx.y << 7;

  floatx4 acc[2][4] = {};
  const short* Ab = A  + (size_t)m0 * C_;
  const short* Bb = Bm + (size_t)n0 * C_;

  for (int k0 = 0; k0 < C_; k0 += 64) {
    __syncthreads();
#pragma unroll
    for (int i = 0; i < 4; ++i) {        // As: 1024 chunks, swizzled granules
      int c = (i<<8) + tid, r = c >> 3, g = (c & 7) ^ (r & 7);
      gll16(&As[((i<<8) + (wv<<6))*8], Ab + (size_t)r*C_ + k0 + (g<<3));
    }
#pragma unroll
    for (int i = 0; i < 2; ++i) {        // Bs: 512 chunks
      int c = (i<<8) + tid, r = c >> 3, g = (c & 7) ^ (r & 7);
      gll16(&Bs[((i<<8) + (wv<<6))*8], Bb + (size_t)r*C_ + k0 + (g<<3));
    }
    __syncthreads();
#pragma unroll
    for (int ks = 0; ks < 2; ++ks) {
      bhalf8 af[2], bfr[4];
#pragma unroll
      for (int rt = 0; rt < 2; ++rt) {
        int row = (wv<<5) + rt*16 + l15;
        af[rt] = *(const bhalf8*)&As[(row<<6) + ((((ks<<2)+quad) ^ (row&7))<<3)];
      }
#pragma unroll
      for (int ct = 0; ct < 4; ++ct) {
        int row = ct*16 + l15;
        bfr[ct] = *(const bhalf8*)&Bs[(row<<6) + ((((ks<<2)+quad) ^ (row&7))<<3)];
      }
#pragma unroll
      for (int rt = 0; rt < 2; ++rt)
#pragma unroll
        for (int ct = 0; ct < 4; ++ct)
          acc[rt][ct] = __builtin_amdgcn_mfma_f32_16x16x32_bf16(af[rt], bfr[ct], acc[rt][ct], 0, 0, 0);
    }
  }

#pragma unroll
  for (int rt = 0; rt < 2; ++rt)
#pragma unroll
    for (int r = 0; r < 4; ++r) {
      int n = m0 + (wv<<5) + rt*16 + quad*4 + r;
#pragma unroll
      for (int ct = 0; ct < 4; ++ct)
        Cf[(size_t)n * C_ + n0 + ct*16 + l15] = acc[rt][ct][r];
    }
}

// One block per (b, h, 128 query rows). Causal decay retention + fused GroupNorm.
// Double-buffered K/V staging, ONE barrier per k-tile. LDS 48KB, 2 blocks/CU,
// launch_bounds(256,2) -> 256-reg budget (R2's (256,4) caused scratch spills).
__global__ __launch_bounds__(256, 2) void retention(
    const short* __restrict__ Qb, const short* __restrict__ Kb, const short* __restrict__ Vt,
    const float* __restrict__ gnw, const float* __restrict__ gnb,
    short* __restrict__ Xn)
{
  __shared__ __align__(16) short Ks[2][64*64];   // XOR-swizzled: granule g at g^(row&7)
  __shared__ __align__(16) short Vs[2][64*64];   // V^T tile [d][s], same swizzle
  __shared__ __align__(16) short Ss[128*64];     // swizzle (row>>1)&7, wave-private rows

  const int tid = threadIdx.x, lane = tid & 63, wv = tid >> 6;
  const int l15 = lane & 15, quad = lane >> 4;

  // XCD-clustering swizzle: all 16 q-blocks of one (b,h) share blockIdx%8
  const int flat = blockIdx.x;
  const int p  = (flat & 7) | (((flat >> 7) & 3) << 3);   // (b,h) pair 0..31
  const int qi = (flat >> 3) & 15;
  const int b = p >> 4, h = p & 15;
  const int n0 = qi << 7;

  const float log2g = log2f(1.f - exp2f(-5.f - (float)h));

  const short* Qg  = Qb + ((size_t)(b*H_ + h)*T_ + n0 + (wv<<5)) * DH_;
  const short* Kg  = Kb + ((size_t)(b*H_ + h)*T_) * DH_;
  const short* Vtg = Vt + (size_t)b*(C_*T_) + (size_t)h*DH_*T_;

  // Q fragments for the wave's 32 rows, kept in registers all loop long
  bhalf8 aq[2][2];
#pragma unroll
  for (int rt = 0; rt < 2; ++rt)
#pragma unroll
    for (int ks = 0; ks < 2; ++ks)
      aq[rt][ks] = *(const bhalf8*)(Qg + (rt*16 + l15)*DH_ + ks*32 + quad*8);

  // decay factors: gamma^(n-m)/8 = rowf(n) * colf0(m) * tilef
  float rowf[2][4], colf0[4];
#pragma unroll
  for (int rt = 0; rt < 2; ++rt)
#pragma unroll
    for (int r = 0; r < 4; ++r)
      rowf[rt][r] = exp2f(log2g * (float)((wv<<5) + rt*16 + (quad<<2) + r)) * 0.125f;
#pragma unroll
  for (int ct = 0; ct < 4; ++ct)
    colf0[ct] = exp2f(-log2g * (float)(ct*16 + l15));

  // first non-fully-decayed tile (block-uniform, monotone)
  int mt0 = 0;
  while (log2g * (float)(n0 - (mt0 << 6) - 63) < -34.f) ++mt0;
  const int mtmax = (n0 >> 6) + 1;

  auto stage = [&](int buf, int mt) {
    const int m0s = mt << 6;
#pragma unroll
    for (int i = 0; i < 2; ++i) {
      int slot = (i<<8) + tid;
      int r = slot >> 3, g = (slot & 7) ^ (r & 7);
      gll16(&Ks[buf][((i<<8) + (wv<<6))*8], Kg  + (size_t)(m0s + r)*DH_ + (g<<3));
      gll16(&Vs[buf][((i<<8) + (wv<<6))*8], Vtg + (size_t)r*T_ + m0s + (g<<3));
    }
  };

  floatx4 oacc[2][4] = {};
  stage(0, mt0);
  int cur = 0;
  for (int mt = mt0; mt <= mtmax; ++mt, cur ^= 1) {
    const int m0 = mt << 6;
    __syncthreads();          // buf[cur] loads drained; prev reads of buf[cur^1] done
    if (mt < mtmax) stage(cur ^ 1, mt + 1);   // overlaps with compute below

    if (m0 <= n0 + (wv<<5) + 31) {            // wave has any unmasked rows
      floatx4 sacc[2][4] = {};
#pragma unroll
      for (int ks = 0; ks < 2; ++ks) {
        bhalf8 bk[4];
#pragma unroll
        for (int ct = 0; ct < 4; ++ct) {
          int row = ct*16 + l15;
          bk[ct] = *(const bhalf8*)&Ks[cur][(row<<6) + ((((ks<<2)+quad) ^ (row&7))<<3)];
        }
#pragma unroll
        for (int rt = 0; rt < 2; ++rt)
#pragma unroll
          for (int ct = 0; ct < 4; ++ct)
            sacc[rt][ct] = __builtin_amdgcn_mfma_f32_16x16x32_bf16(aq[rt][ks], bk[ct], sacc[rt][ct], 0, 0, 0);
      }

      const float tilef = exp2f(log2g * (float)(n0 - m0));
      const bool maskT = (m0 + 64 > n0);
#pragma unroll
      for (int rt = 0; rt < 2; ++rt)
#pragma unroll
        for (int ct = 0; ct < 4; ++ct) {
          float cf = colf0[ct] * tilef;
          int colg = (ct<<1) + (l15>>3);
#pragma unroll
          for (int r = 0; r < 4; ++r) {
            int row = (wv<<5) + rt*16 + (quad<<2) + r;
            float v = sacc[rt][ct][r] * (rowf[rt][r] * cf);
            if (maskT && (n0 + row) < (m0 + ct*16 + l15)) v = 0.f;
            Ss[(row<<6) + ((colg ^ ((row>>1)&7))<<3) + (l15&7)] = f2bf(v);
          }
        }
      // no barrier: wave reads back only its own Ss rows (lgkmcnt ordering)

#pragma unroll
      for (int ks = 0; ks < 2; ++ks) {
        bhalf8 as_[2], bv[4];
#pragma unroll
        for (int rt = 0; rt < 2; ++rt) {
          int row = (wv<<5) + rt*16 + l15;
          as_[rt] = *(const bhalf8*)&Ss[(row<<6) + ((((ks<<2)+quad) ^ ((row>>1)&7))<<3)];
        }
#pragma unroll
        for (int ct = 0; ct < 4; ++ct) {
          int row = ct*16 + l15;
          bv[ct] = *(const bhalf8*)&Vs[cur][(row<<6) + ((((ks<<2)+quad) ^ (row&7))<<3)];
        }
#pragma unroll
        for (int rt = 0; rt < 2; ++rt)
#pragma unroll
          for (int ct = 0; ct < 4; ++ct)
            oacc[rt][ct] = __builtin_amdgcn_mfma_f32_16x16x32_bf16(as_[rt], bv[ct], oacc[rt][ct], 0, 0, 0);
      }
    }
  }

  // fused GroupNorm over DH, write (B,T,C) bf16
#pragma unroll
  for (int rt = 0; rt < 2; ++rt)
#pragma unroll
    for (int r = 0; r < 4; ++r) {
      float s1 = oacc[rt][0][r] + oacc[rt][1][r] + oacc[rt][2][r] + oacc[rt][3][r];
      float s2 = oacc[rt][0][r]*oacc[rt][0][r] + oacc[rt][1][r]*oacc[rt][1][r]
               + oacc[rt][2][r]*oacc[rt][2][r] + oacc[rt][3][r]*oacc[rt][3][r];
#pragma unroll
      for (int off = 1; off < 16; off <<= 1) {
        s1 += __shfl_xor(s1, off);
        s2 += __shfl_xor(s2, off);
      }
      float mean = s1 * (1.f/64.f);
      float var  = s2 * (1.f/64.f) - mean*mean;
      float rstd = rsqrtf(var + 1e-5f);
      int t = n0 + (wv<<5) + rt*16 + (quad<<2) + r;
      size_t obase = ((size_t)b*T_ + t)*C_ + h*DH_;
#pragma unroll
      for (int ct = 0; ct < 4; ++ct) {
        int d = ct*16 + l15;
        float y = (oacc[rt][ct][r] - mean)*rstd*gnw[h*DH_ + d] + gnb[h*DH_ + d];
        Xn[obase + d] = f2bf(y);
      }
    }
}

extern "C" void kernel_launch(void* const* d_in, const int* in_sizes, int n_in,
                              void* d_out, int out_size, void* d_ws, size_t ws_size,
                              hipStream_t stream) {
  (void)in_sizes; (void)n_in; (void)out_size; (void)ws_size;
  const float* x   = (const float*)d_in[0];
  const float* Wq  = (const float*)d_in[1];
  const float* Wk  = (const float*)d_in[2];
  const float* Wv  = (const float*)d_in[3];
  const float* Wo  = (const float*)d_in[4];
  const float* gnw = (const float*)d_in[5];
  const float* gnb = (const float*)d_in[6];
  float* out = (float*)d_out;

  char* ws = (char*)d_ws;                 // 48 MB used
  short* Xb  = (short*)(ws);              // x bf16:  4096x1024 (8 MB)
  short* Wqb = (short*)(ws + (8u<<20));   // 2 MB each
  short* Wkb = (short*)(ws + (10u<<20));
  short* Wvb = (short*)(ws + (12u<<20));
  short* Wob = (short*)(ws + (14u<<20));
  short* Qb  = (short*)(ws + (16u<<20));  // (B,H,T,DH) bf16, 8 MB each
  short* Kb  = (short*)(ws + (24u<<20));
  short* Vtw = (short*)(ws + (32u<<20));  // V^T (B,H,DH,T) bf16
  short* Xn  = (short*)(ws + (40u<<20));  // normalized retention out (B,T,C) bf16

  cvt_bf16<<<(M_*C_/4 + 255)/256, 256, 0, stream>>>(x,  Xb,  M_*C_/4);
  cvt_bf16<<<(C_*C_/4 + 255)/256, 256, 0, stream>>>(Wq, Wqb, C_*C_/4);
  cvt_bf16<<<(C_*C_/4 + 255)/256, 256, 0, stream>>>(Wk, Wkb, C_*C_/4);
  cvt_bf16<<<(C_*C_/4 + 255)/256, 256, 0, stream>>>(Wv, Wvb, C_*C_/4);
  cvt_bf16<<<(C_*C_/4 + 255)/256, 256, 0, stream>>>(Wo, Wob, C_*C_/4);

  gemm_qkv<<<dim3(24, 32), 256, 0, stream>>>(Xb, Wqb, Wkb, Wvb, Qb, Kb, Vtw);
  retention<<<512, 256, 0, stream>>>(Qb, Kb, Vtw, gnw, gnb, Xn);
  gemm_out<<<dim3(16, 32), 256, 0, stream>>>(Xn, Wob, out);
}

// Round 4
// 204.435 us; speedup vs baseline: 1.7926x; 1.0569x over previous
//
#include <hip/hip_runtime.h>
#include <stdint.h>

#define B_ 2
#define T_ 2048
#define C_ 1024
#define H_ 16
#define DH_ 64
#define M_ (B_*T_)   // 4096

typedef short bhalf8 __attribute__((ext_vector_type(8)));
typedef float floatx4 __attribute__((ext_vector_type(4)));

__device__ __forceinline__ short f2bf(float f) {
  unsigned u = __float_as_uint(f);
  u += 0x7fffu + ((u >> 16) & 1u);   // round-to-nearest-even
  return (short)(u >> 16);
}

// async global->LDS, 16B per lane; lds_dst must be wave-uniform (lane data
// lands at lds_dst + lane*16)
__device__ __forceinline__ void gll16(void* lds_dst, const void* g_src) {
  __builtin_amdgcn_global_load_lds(
      reinterpret_cast<const uint32_t __attribute__((address_space(1)))*>(
          reinterpret_cast<uintptr_t>(g_src)),
      reinterpret_cast<uint32_t __attribute__((address_space(3)))*>(
          reinterpret_cast<uintptr_t>(lds_dst)),
      16, 0, 0);
}

// One launch converts x + all 4 weights (fp32 -> bf16), float4 granularity.
__global__ void cvt_all(
    const float* __restrict__ x,  const float* __restrict__ wq,
    const float* __restrict__ wk, const float* __restrict__ wv,
    const float* __restrict__ wo,
    short* __restrict__ xb, short* __restrict__ wqb, short* __restrict__ wkb,
    short* __restrict__ wvb, short* __restrict__ wob)
{
  int i = blockIdx.x * blockDim.x + threadIdx.x;
  const float* s; short* d; int off;
  if (i < (M_*C_/4)) { s = x; d = xb; off = i; }
  else {
    int j = i - M_*C_/4;
    int w = j >> 18;                     // C_*C_/4 == 1<<18
    off = j & ((1<<18) - 1);
    s = (w==0) ? wq : (w==1) ? wk : (w==2) ? wv : wo;
    d = (w==0) ? wqb : (w==1) ? wkb : (w==2) ? wvb : wob;
  }
  float4 v = ((const float4*)s)[off];
  short4 o;
  o.x = f2bf(v.x); o.y = f2bf(v.y); o.z = f2bf(v.z); o.w = f2bf(v.w);
  ((short4*)d)[off] = o;
}

// Fused Q/K/V projection. Grid (24, 32): x<8 -> Q-tile, x<16 -> K-tile,
// x>=16 -> V-tile (operands swapped so C/D layout gives coalesced V^T store).
// 768 blocks = 3/CU.
__global__ __launch_bounds__(256) void gemm_qkv(
    const short* __restrict__ X,
    const short* __restrict__ Wq, const short* __restrict__ Wk, const short* __restrict__ Wv,
    short* __restrict__ Qb, short* __restrict__ Kb, short* __restrict__ Vt)
{
  __shared__ __align__(16) short As[128*32];
  __shared__ __align__(16) short Bs[128*32];
  const int tid  = threadIdx.x;
  const int lane = tid & 63;
  const int wv   = tid >> 6;
  const int l15  = lane & 15;
  const int quad = lane >> 4;
  const int wm   = (wv >> 1) << 6;   // wave row offset (2x2 wave grid)
  const int wn   = (wv & 1) << 6;    // wave col offset
  const int nx   = blockIdx.x;
  const int m0   = blockIdx.y << 7;
  const int K    = C_;

  const short *Ab, *Bb;
  int nloc, kind;                    // 0=Q 1=K 2=V
  if (nx < 8)       { kind = 0; nloc = nx << 7;        Ab = X  + (size_t)m0*K;   Bb = Wq + (size_t)nloc*K; }
  else if (nx < 16) { kind = 1; nloc = (nx - 8) << 7;  Ab = X  + (size_t)m0*K;   Bb = Wk + (size_t)nloc*K; }
  else              { kind = 2; nloc = (nx - 16) << 7; Ab = Wv + (size_t)nloc*K; Bb = X  + (size_t)m0*K;   }

  floatx4 acc[4][4] = {};

  for (int k0 = 0; k0 < K; k0 += 32) {
    __syncthreads();                     // LDS reuse guard
#pragma unroll
    for (int i = 0; i < 2; ++i) {
      int c = i*256 + tid;               // 512 chunks of 16B per tile
      int row = c >> 2, off = (c & 3) * 8;
      gll16(&As[(i*256 + (wv<<6))*8], Ab + (size_t)row*K + k0 + off);
      gll16(&Bs[(i*256 + (wv<<6))*8], Bb + (size_t)row*K + k0 + off);
    }
    __syncthreads();                     // vmcnt drain at barrier
    bhalf8 af[4], bfr[4];
#pragma unroll
    for (int rt = 0; rt < 4; ++rt)
      af[rt] = *(const bhalf8*)&As[(wm + rt*16 + l15)*32 + quad*8];
#pragma unroll
    for (int ct = 0; ct < 4; ++ct)
      bfr[ct] = *(const bhalf8*)&Bs[(wn + ct*16 + l15)*32 + quad*8];
#pragma unroll
    for (int rt = 0; rt < 4; ++rt)
#pragma unroll
      for (int ct = 0; ct < 4; ++ct)
        acc[rt][ct] = __builtin_amdgcn_mfma_f32_16x16x32_bf16(af[rt], bfr[ct], acc[rt][ct], 0, 0, 0);
  }

  if (kind < 2) {                        // Q or K: RoPE epilogue -> (B,H,T,DH)
    short* Cb = kind ? Kb : Qb;
    const int hh = (nloc + wn) >> 6;     // wave covers exactly one head
#pragma unroll
    for (int rt = 0; rt < 4; ++rt)
#pragma unroll
      for (int r = 0; r < 4; ++r) {
        int n  = m0 + wm + rt*16 + quad*4 + r;
        int bb = n >> 11, t = n & (T_-1);
        size_t base = ((size_t)(bb*H_ + hh)*T_ + t)*DH_;
        float tf = (float)t;
#pragma unroll
        for (int ct = 0; ct < 2; ++ct) {
          int ii = ct*16 + l15;          // freq index 0..31
          float ang = tf * exp2f((float)ii * (-0.4152410118609203f));
          float sn = __sinf(ang), cs = __cosf(ang);
          float xlo = acc[rt][ct][r], xhi = acc[rt][ct+2][r];
          Cb[base + ii]      = f2bf(xlo*cs - xhi*sn);
          Cb[base + ii + 32] = f2bf(xhi*cs + xlo*sn);
        }
      }
  } else {                               // V: rows=channels, cols=tokens -> V^T store
#pragma unroll
    for (int rt = 0; rt < 4; ++rt)
#pragma unroll
      for (int r = 0; r < 4; ++r) {
        int o = nloc + wm + rt*16 + quad*4 + r;   // channel
#pragma unroll
        for (int ct = 0; ct < 4; ++ct) {
          int n  = m0 + wn + ct*16 + l15;         // token
          int bb = n >> 11, t = n & (T_-1);
          Vt[(size_t)bb*(C_*T_) + (size_t)o*T_ + t] = f2bf(acc[rt][ct][r]);
        }
      }
  }
}

// Final projection: C = Xn(4096 x 1024) @ Wo^T, fp32 out.
// M-tile 128, N-tile 64, BK 64, XOR-swizzled LDS. 512 blocks = 2/CU.
__global__ __launch_bounds__(256) void gemm_out(
    const short* __restrict__ A, const short* __restrict__ Bm, float* __restrict__ Cf)
{
  __shared__ __align__(16) short As[128*64];
  __shared__ __align__(16) short Bs[64*64];
  const int tid = threadIdx.x, lane = tid & 63, wv = tid >> 6;
  const int l15 = lane & 15, quad = lane >> 4;
  const int n0 = blockIdx.x << 6;
  const int m0 = blockIdx.y << 7;

  floatx4 acc[2][4] = {};
  const short* Ab = A  + (size_t)m0 * C_;
  const short* Bb = Bm + (size_t)n0 * C_;

  for (int k0 = 0; k0 < C_; k0 += 64) {
    __syncthreads();
#pragma unroll
    for (int i = 0; i < 4; ++i) {        // As: 1024 chunks, swizzled granules
      int c = (i<<8) + tid, r = c >> 3, g = (c & 7) ^ (r & 7);
      gll16(&As[((i<<8) + (wv<<6))*8], Ab + (size_t)r*C_ + k0 + (g<<3));
    }
#pragma unroll
    for (int i = 0; i < 2; ++i) {        // Bs: 512 chunks
      int c = (i<<8) + tid, r = c >> 3, g = (c & 7) ^ (r & 7);
      gll16(&Bs[((i<<8) + (wv<<6))*8], Bb + (size_t)r*C_ + k0 + (g<<3));
    }
    __syncthreads();
#pragma unroll
    for (int ks = 0; ks < 2; ++ks) {
      bhalf8 af[2], bfr[4];
#pragma unroll
      for (int rt = 0; rt < 2; ++rt) {
        int row = (wv<<5) + rt*16 + l15;
        af[rt] = *(const bhalf8*)&As[(row<<6) + ((((ks<<2)+quad) ^ (row&7))<<3)];
      }
#pragma unroll
      for (int ct = 0; ct < 4; ++ct) {
        int row = ct*16 + l15;
        bfr[ct] = *(const bhalf8*)&Bs[(row<<6) + ((((ks<<2)+quad) ^ (row&7))<<3)];
      }
#pragma unroll
      for (int rt = 0; rt < 2; ++rt)
#pragma unroll
        for (int ct = 0; ct < 4; ++ct)
          acc[rt][ct] = __builtin_amdgcn_mfma_f32_16x16x32_bf16(af[rt], bfr[ct], acc[rt][ct], 0, 0, 0);
    }
  }

#pragma unroll
  for (int rt = 0; rt < 2; ++rt)
#pragma unroll
    for (int r = 0; r < 4; ++r) {
      int n = m0 + (wv<<5) + rt*16 + quad*4 + r;
#pragma unroll
      for (int ct = 0; ct < 4; ++ct)
        Cf[(size_t)n * C_ + n0 + ct*16 + l15] = acc[rt][ct][r];
    }
}

// Retention: one block per (b, h, 64 query rows). 1024 blocks = 4/CU.
// LDS 40KB (K/V dbuf + wave-private Ss). Strips interleaved light/heavy for
// per-CU balance. Double-buffered staging, one barrier per k-tile.
__global__ __launch_bounds__(256, 4) void retention(
    const short* __restrict__ Qb, const short* __restrict__ Kb, const short* __restrict__ Vt,
    const float* __restrict__ gnw, const float* __restrict__ gnb,
    short* __restrict__ Xn)
{
  __shared__ __align__(16) short Ks[2][64*64];   // XOR-swizzled: granule g at g^(row&7)
  __shared__ __align__(16) short Vs[2][64*64];   // V^T tile [d][s], same swizzle
  __shared__ __align__(16) short Ss[64*64];      // swizzle (row>>1)&7, wave-private rows

  const int tid = threadIdx.x, lane = tid & 63, wv = tid >> 6;
  const int l15 = lane & 15, quad = lane >> 4;

  // flat -> (b,h,strip): same (b,h) on one XCD-class; strips interleaved
  // light/heavy (0,31,1,30,...) so consecutive blocks carry complementary work.
  const int flat = blockIdx.x;
  const int bh = (flat & 7) | (((flat >> 8) & 3) << 3);
  const int si = (flat >> 3) & 31;
  const int s  = (si & 1) ? (31 - (si >> 1)) : (si >> 1);
  const int b = bh >> 4, h = bh & 15;
  const int n0 = s << 6;

  const float log2g = log2f(1.f - exp2f(-5.f - (float)h));

  const short* Qg  = Qb + ((size_t)(b*H_ + h)*T_ + n0 + (wv<<4)) * DH_;
  const short* Kg  = Kb + ((size_t)(b*H_ + h)*T_) * DH_;
  const short* Vtg = Vt + (size_t)b*(C_*T_) + (size_t)h*DH_*T_;

  // Q fragments for the wave's 16 rows, in registers all loop long
  bhalf8 aq[2];
#pragma unroll
  for (int ks = 0; ks < 2; ++ks)
    aq[ks] = *(const bhalf8*)(Qg + (size_t)l15*DH_ + ks*32 + quad*8);

  // decay: gamma^(n-m)/8 = rowf(row) * colf0(col) * tilef(tile)
  float rowf[4], colf0[4];
#pragma unroll
  for (int r = 0; r < 4; ++r)
    rowf[r] = exp2f(log2g * (float)((wv<<4) + (quad<<2) + r)) * 0.125f;
#pragma unroll
  for (int ct = 0; ct < 4; ++ct)
    colf0[ct] = exp2f(-log2g * (float)(ct*16 + l15));

  // first non-fully-decayed tile (block-uniform, monotone)
  int mt0 = 0;
  while (log2g * (float)(n0 - (mt0 << 6) - 63) < -34.f) ++mt0;
  const int mtmax = s;                         // diagonal tile

  auto stage = [&](int buf, int mt) {
    const int m0s = mt << 6;
#pragma unroll
    for (int i = 0; i < 2; ++i) {
      int slot = (i<<8) + tid;
      int r = slot >> 3, g = (slot & 7) ^ (r & 7);
      gll16(&Ks[buf][((i<<8) + (wv<<6))*8], Kg  + (size_t)(m0s + r)*DH_ + (g<<3));
      gll16(&Vs[buf][((i<<8) + (wv<<6))*8], Vtg + (size_t)r*T_ + m0s + (g<<3));
    }
  };

  floatx4 oacc[4] = {};
  stage(0, mt0);
  int cur = 0;
  for (int mt = mt0; mt <= mtmax; ++mt, cur ^= 1) {
    const int m0 = mt << 6;
    __syncthreads();          // buf[cur] drained; prev reads of buf[cur^1] done
    if (mt < mtmax) stage(cur ^ 1, mt + 1);    // overlaps with compute below

    floatx4 sacc[4] = {};
#pragma unroll
    for (int ks = 0; ks < 2; ++ks) {
      bhalf8 bk[4];
#pragma unroll
      for (int ct = 0; ct < 4; ++ct) {
        int row = ct*16 + l15;
        bk[ct] = *(const bhalf8*)&Ks[cur][(row<<6) + ((((ks<<2)+quad) ^ (row&7))<<3)];
      }
#pragma unroll
      for (int ct = 0; ct < 4; ++ct)
        sacc[ct] = __builtin_amdgcn_mfma_f32_16x16x32_bf16(aq[ks], bk[ct], sacc[ct], 0, 0, 0);
    }

    const float tilef = exp2f(log2g * (float)(n0 - m0));
    if (mt == mtmax) {                         // diagonal tile: causal mask
#pragma unroll
      for (int ct = 0; ct < 4; ++ct) {
        float cf = colf0[ct] * tilef;
        int colg = (ct<<1) + (l15>>3);
        int m = m0 + ct*16 + l15;
#pragma unroll
        for (int r = 0; r < 4; ++r) {
          int row = (wv<<4) + (quad<<2) + r;
          float v = (n0 + row >= m) ? sacc[ct][r] * (rowf[r] * cf) : 0.f;
          Ss[(row<<6) + ((colg ^ ((row>>1)&7))<<3) + (l15&7)] = f2bf(v);
        }
      }
    } else {
#pragma unroll
      for (int ct = 0; ct < 4; ++ct) {
        float cf = colf0[ct] * tilef;
        int colg = (ct<<1) + (l15>>3);
#pragma unroll
        for (int r = 0; r < 4; ++r) {
          int row = (wv<<4) + (quad<<2) + r;
          Ss[(row<<6) + ((colg ^ ((row>>1)&7))<<3) + (l15&7)] = f2bf(sacc[ct][r] * (rowf[r] * cf));
        }
      }
    }
    // no barrier: wave reads back only its own Ss rows (lgkmcnt ordering)

#pragma unroll
    for (int ks = 0; ks < 2; ++ks) {
      int row = (wv<<4) + l15;
      bhalf8 as_ = *(const bhalf8*)&Ss[(row<<6) + ((((ks<<2)+quad) ^ ((row>>1)&7))<<3)];
      bhalf8 bv[4];
#pragma unroll
      for (int ct = 0; ct < 4; ++ct) {
        int vrow = ct*16 + l15;
        bv[ct] = *(const bhalf8*)&Vs[cur][(vrow<<6) + ((((ks<<2)+quad) ^ (vrow&7))<<3)];
      }
#pragma unroll
      for (int ct = 0; ct < 4; ++ct)
        oacc[ct] = __builtin_amdgcn_mfma_f32_16x16x32_bf16(as_, bv[ct], oacc[ct], 0, 0, 0);
    }
  }

  // fused GroupNorm over DH, write (B,T,C) bf16
#pragma unroll
  for (int r = 0; r < 4; ++r) {
    float s1 = oacc[0][r] + oacc[1][r] + oacc[2][r] + oacc[3][r];
    float s2 = oacc[0][r]*oacc[0][r] + oacc[1][r]*oacc[1][r]
             + oacc[2][r]*oacc[2][r] + oacc[3][r]*oacc[3][r];
#pragma unroll
    for (int off = 1; off < 16; off <<= 1) {
      s1 += __shfl_xor(s1, off);
      s2 += __shfl_xor(s2, off);
    }
    float mean = s1 * (1.f/64.f);
    float var  = s2 * (1.f/64.f) - mean*mean;
    float rstd = rsqrtf(var + 1e-5f);
    int t = n0 + (wv<<4) + (quad<<2) + r;
    size_t obase = ((size_t)b*T_ + t)*C_ + h*DH_;
#pragma unroll
    for (int ct = 0; ct < 4; ++ct) {
      int d = ct*16 + l15;
      float y = (oacc[ct][r] - mean)*rstd*gnw[h*DH_ + d] + gnb[h*DH_ + d];
      Xn[obase + d] = f2bf(y);
    }
  }
}

extern "C" void kernel_launch(void* const* d_in, const int* in_sizes, int n_in,
                              void* d_out, int out_size, void* d_ws, size_t ws_size,
                              hipStream_t stream) {
  (void)in_sizes; (void)n_in; (void)out_size; (void)ws_size;
  const float* x   = (const float*)d_in[0];
  const float* Wq  = (const float*)d_in[1];
  const float* Wk  = (const float*)d_in[2];
  const float* Wv  = (const float*)d_in[3];
  const float* Wo  = (const float*)d_in[4];
  const float* gnw = (const float*)d_in[5];
  const float* gnb = (const float*)d_in[6];
  float* out = (float*)d_out;

  char* ws = (char*)d_ws;                 // 48 MB used
  short* Xb  = (short*)(ws);              // x bf16:  4096x1024 (8 MB)
  short* Wqb = (short*)(ws + (8u<<20));   // 2 MB each
  short* Wkb = (short*)(ws + (10u<<20));
  short* Wvb = (short*)(ws + (12u<<20));
  short* Wob = (short*)(ws + (14u<<20));
  short* Qb  = (short*)(ws + (16u<<20));  // (B,H,T,DH) bf16, 8 MB each
  short* Kb  = (short*)(ws + (24u<<20));
  short* Vtw = (short*)(ws + (32u<<20));  // V^T (B,H,DH,T) bf16
  short* Xn  = (short*)(ws + (40u<<20));  // normalized retention out (B,T,C) bf16

  cvt_all<<<(M_*C_/4 + 4*(C_*C_/4)) / 256, 256, 0, stream>>>(
      x, Wq, Wk, Wv, Wo, Xb, Wqb, Wkb, Wvb, Wob);

  gemm_qkv<<<dim3(24, 32), 256, 0, stream>>>(Xb, Wqb, Wkb, Wvb, Qb, Kb, Vtw);
  retention<<<1024, 256, 0, stream>>>(Qb, Kb, Vtw, gnw, gnb, Xn);
  gemm_out<<<dim3(16, 32), 256, 0, stream>>>(Xn, Wob, out);
}

// Round 7
// 187.570 us; speedup vs baseline: 1.9538x; 1.0899x over previous
//
#include <hip/hip_runtime.h>
#include <stdint.h>

#define B_ 2
#define T_ 2048
#define C_ 1024
#define H_ 16
#define DH_ 64
#define M_ (B_*T_)   // 4096

typedef short bhalf8 __attribute__((ext_vector_type(8)));
typedef float floatx4 __attribute__((ext_vector_type(4)));

__device__ __forceinline__ short f2bf(float f) {
  unsigned u = __float_as_uint(f);
  u += 0x7fffu + ((u >> 16) & 1u);   // round-to-nearest-even
  return (short)(u >> 16);
}
__device__ __forceinline__ float bf2f(short s) {
  return __uint_as_float(((unsigned)(unsigned short)s) << 16);
}

// async global->LDS, 16B per lane; lds_dst wave-uniform (lane -> +lane*16)
__device__ __forceinline__ void gll16(void* lds_dst, const void* g_src) {
  __builtin_amdgcn_global_load_lds(
      reinterpret_cast<const uint32_t __attribute__((address_space(1)))*>(
          reinterpret_cast<uintptr_t>(g_src)),
      reinterpret_cast<uint32_t __attribute__((address_space(3)))*>(
          reinterpret_cast<uintptr_t>(lds_dst)),
      16, 0, 0);
}

__global__ void cvt_all(
    const float* __restrict__ x,  const float* __restrict__ wq,
    const float* __restrict__ wk, const float* __restrict__ wv,
    const float* __restrict__ wo,
    short* __restrict__ xb, short* __restrict__ wqb, short* __restrict__ wkb,
    short* __restrict__ wvb, short* __restrict__ wob)
{
  int i = blockIdx.x * blockDim.x + threadIdx.x;
  const float* s; short* d; int off;
  if (i < (M_*C_/4)) { s = x; d = xb; off = i; }
  else {
    int j = i - M_*C_/4;
    int w = j >> 18;                     // C_*C_/4 == 1<<18
    off = j & ((1<<18) - 1);
    s = (w==0) ? wq : (w==1) ? wk : (w==2) ? wv : wo;
    d = (w==0) ? wqb : (w==1) ? wkb : (w==2) ? wvb : wob;
  }
  float4 v = ((const float4*)s)[off];
  short4 o;
  o.x = f2bf(v.x); o.y = f2bf(v.y); o.z = f2bf(v.z); o.w = f2bf(v.w);
  ((short4*)d)[off] = o;
}

// Fused Q/K/V projection. Grid (24,32).
__global__ __launch_bounds__(256) void gemm_qkv(
    const short* __restrict__ X,
    const short* __restrict__ Wq, const short* __restrict__ Wk, const short* __restrict__ Wv,
    short* __restrict__ Qb, short* __restrict__ Kb, short* __restrict__ Vt)
{
  __shared__ __align__(16) short As[128*32];
  __shared__ __align__(16) short Bs[128*32];
  const int tid  = threadIdx.x;
  const int lane = tid & 63;
  const int wv   = tid >> 6;
  const int l15  = lane & 15;
  const int quad = lane >> 4;
  const int wm   = (wv >> 1) << 6;
  const int wn   = (wv & 1) << 6;
  const int nx   = blockIdx.x;
  const int m0   = blockIdx.y << 7;
  const int K    = C_;

  const short *Ab, *Bb;
  int nloc, kind;                    // 0=Q 1=K 2=V
  if (nx < 8)       { kind = 0; nloc = nx << 7;        Ab = X  + (size_t)m0*K;   Bb = Wq + (size_t)nloc*K; }
  else if (nx < 16) { kind = 1; nloc = (nx - 8) << 7;  Ab = X  + (size_t)m0*K;   Bb = Wk + (size_t)nloc*K; }
  else              { kind = 2; nloc = (nx - 16) << 7; Ab = Wv + (size_t)nloc*K; Bb = X  + (size_t)m0*K;   }

  floatx4 acc[4][4] = {};

  for (int k0 = 0; k0 < K; k0 += 32) {
    __syncthreads();
#pragma unroll
    for (int i = 0; i < 2; ++i) {
      int c = i*256 + tid;
      int row = c >> 2, off = (c & 3) * 8;
      gll16(&As[(i*256 + (wv<<6))*8], Ab + (size_t)row*K + k0 + off);
      gll16(&Bs[(i*256 + (wv<<6))*8], Bb + (size_t)row*K + k0 + off);
    }
    __syncthreads();
    bhalf8 af[4], bfr[4];
#pragma unroll
    for (int rt = 0; rt < 4; ++rt)
      af[rt] = *(const bhalf8*)&As[(wm + rt*16 + l15)*32 + quad*8];
#pragma unroll
    for (int ct = 0; ct < 4; ++ct)
      bfr[ct] = *(const bhalf8*)&Bs[(wn + ct*16 + l15)*32 + quad*8];
#pragma unroll
    for (int rt = 0; rt < 4; ++rt)
#pragma unroll
      for (int ct = 0; ct < 4; ++ct)
        acc[rt][ct] = __builtin_amdgcn_mfma_f32_16x16x32_bf16(af[rt], bfr[ct], acc[rt][ct], 0, 0, 0);
  }

  if (kind < 2) {
    short* Cb = kind ? Kb : Qb;
    const int hh = (nloc + wn) >> 6;
#pragma unroll
    for (int rt = 0; rt < 4; ++rt)
#pragma unroll
      for (int r = 0; r < 4; ++r) {
        int n  = m0 + wm + rt*16 + quad*4 + r;
        int bb = n >> 11, t = n & (T_-1);
        size_t base = ((size_t)(bb*H_ + hh)*T_ + t)*DH_;
        float tf = (float)t;
#pragma unroll
        for (int ct = 0; ct < 2; ++ct) {
          int ii = ct*16 + l15;
          float ang = tf * exp2f((float)ii * (-0.4152410118609203f));
          float sn = __sinf(ang), cs = __cosf(ang);
          float xlo = acc[rt][ct][r], xhi = acc[rt][ct+2][r];
          Cb[base + ii]      = f2bf(xlo*cs - xhi*sn);
          Cb[base + ii + 32] = f2bf(xhi*cs + xlo*sn);
        }
      }
  } else {
#pragma unroll
    for (int rt = 0; rt < 4; ++rt)
#pragma unroll
      for (int r = 0; r < 4; ++r) {
        int o = nloc + wm + rt*16 + quad*4 + r;
#pragma unroll
        for (int ct = 0; ct < 4; ++ct) {
          int n  = m0 + wn + ct*16 + l15;
          int bb = n >> 11, t = n & (T_-1);
          Vt[(size_t)bb*(C_*T_) + (size_t)o*T_ + t] = f2bf(acc[rt][ct][r]);
        }
      }
  }
}

// Final projection.
__global__ __launch_bounds__(256) void gemm_out(
    const short* __restrict__ A, const short* __restrict__ Bm, float* __restrict__ Cf)
{
  __shared__ __align__(16) short As[128*64];
  __shared__ __align__(16) short Bs[64*64];
  const int tid = threadIdx.x, lane = tid & 63, wv = tid >> 6;
  const int l15 = lane & 15, quad = lane >> 4;
  const int n0 = blockIdx.x << 6;
  const int m0 = blockIdx.y << 7;

  floatx4 acc[2][4] = {};
  const short* Ab = A  + (size_t)m0 * C_;
  const short* Bb = Bm + (size_t)n0 * C_;

  for (int k0 = 0; k0 < C_; k0 += 64) {
    __syncthreads();
#pragma unroll
    for (int i = 0; i < 4; ++i) {
      int c = (i<<8) + tid, r = c >> 3, g = (c & 7) ^ (r & 7);
      gll16(&As[((i<<8) + (wv<<6))*8], Ab + (size_t)r*C_ + k0 + (g<<3));
    }
#pragma unroll
    for (int i = 0; i < 2; ++i) {
      int c = (i<<8) + tid, r = c >> 3, g = (c & 7) ^ (r & 7);
      gll16(&Bs[((i<<8) + (wv<<6))*8], Bb + (size_t)r*C_ + k0 + (g<<3));
    }
    __syncthreads();
#pragma unroll
    for (int ks = 0; ks < 2; ++ks) {
      bhalf8 af[2], bfr[4];
#pragma unroll
      for (int rt = 0; rt < 2; ++rt) {
        int row = (wv<<5) + rt*16 + l15;
        af[rt] = *(const bhalf8*)&As[(row<<6) + ((((ks<<2)+quad) ^ (row&7))<<3)];
      }
#pragma unroll
      for (int ct = 0; ct < 4; ++ct) {
        int row = ct*16 + l15;
        bfr[ct] = *(const bhalf8*)&Bs[(row<<6) + ((((ks<<2)+quad) ^ (row&7))<<3)];
      }
#pragma unroll
      for (int rt = 0; rt < 2; ++rt)
#pragma unroll
        for (int ct = 0; ct < 4; ++ct)
          acc[rt][ct] = __builtin_amdgcn_mfma_f32_16x16x32_bf16(af[rt], bfr[ct], acc[rt][ct], 0, 0, 0);
    }
  }

#pragma unroll
  for (int rt = 0; rt < 2; ++rt)
#pragma unroll
    for (int r = 0; r < 4; ++r) {
      int n = m0 + (wv<<5) + rt*16 + quad*4 + r;
#pragma unroll
      for (int ct = 0; ct < 4; ++ct)
        Cf[(size_t)n * C_ + n0 + ct*16 + l15] = acc[rt][ct][r];
    }
}

// K (B,H,T,DH) -> Kt (B,H,DH,T). Grid 1024 = bh*32 + token-chunk.
__global__ __launch_bounds__(256) void transpose_k(
    const short* __restrict__ Kb, short* __restrict__ Kt)
{
  __shared__ short tile[64*66];
  const int idx = blockIdx.x, bh = idx >> 5, tc = idx & 31;
  const int t0 = tc << 6;
  const short* src = Kb + ((size_t)bh*T_ + t0) * DH_;
  int row = threadIdx.x >> 2, c0 = (threadIdx.x & 3) << 4;
  *(int4*)&tile[row*66 + c0]     = *(const int4*)&src[row*64 + c0];
  *(int4*)&tile[row*66 + c0 + 8] = *(const int4*)&src[row*64 + c0 + 8];
  __syncthreads();
  short* dst = Kt + (size_t)bh*DH_*T_;
  int d = threadIdx.x >> 2, k0 = (threadIdx.x & 3) << 4;
  short tmp[16];
#pragma unroll
  for (int i = 0; i < 16; ++i) tmp[i] = tile[(k0 + i)*66 + d];
  *(int4*)&dst[(size_t)d*T_ + t0 + k0]     = *(const int4*)&tmp[0];
  *(int4*)&dst[(size_t)d*T_ + t0 + k0 + 8] = *(const int4*)&tmp[8];
}

// Per-segment state summaries. Grid 128 = bh*4 + p.
__global__ __launch_bounds__(256) void seg_state(
    const short* __restrict__ Kt, const short* __restrict__ Vt,
    short* __restrict__ Pseg)
{
  __shared__ __align__(16) short Ks[64*64];   // K^T [d][tok], swizzled
  __shared__ __align__(16) short Vs[64*64];   // V^T [e][tok], swizzled
  const int tid = threadIdx.x, lane = tid & 63, wv = tid >> 6;
  const int l15 = lane & 15, quad = lane >> 4;
  const int wrow = wv << 4;
  const int bh = blockIdx.x >> 2, p = blockIdx.x & 3;
  const int h = bh & 15;
  const float log2g = log2f(1.f - exp2f(-5.f - (float)h));
  const float g64 = exp2f(log2g * 64.f);

  float wgt[16];
#pragma unroll
  for (int ks = 0; ks < 2; ++ks)
#pragma unroll
    for (int i = 0; i < 8; ++i)
      wgt[ks*8 + i] = exp2f(log2g * (float)(64 - (ks*32 + (quad<<3) + i)));

  const short* Ktg = Kt + (size_t)bh*DH_*T_;
  const short* Vtg = Vt + (size_t)bh*DH_*T_;

  floatx4 acc[4] = {};
  for (int j = 0; j < 8; ++j) {
    const int m0 = ((p<<3) + j) << 6;
    __syncthreads();
#pragma unroll
    for (int i = 0; i < 2; ++i) {
      int slot = (i<<8) + tid;
      int r = slot >> 3, g = (slot & 7) ^ (r & 7);
      gll16(&Ks[((i<<8) + (wv<<6))*8], Ktg + (size_t)r*T_ + m0 + (g<<3));
      gll16(&Vs[((i<<8) + (wv<<6))*8], Vtg + (size_t)r*T_ + m0 + (g<<3));
    }
    __syncthreads();
#pragma unroll
    for (int ct = 0; ct < 4; ++ct)
#pragma unroll
      for (int r = 0; r < 4; ++r) acc[ct][r] *= g64;
#pragma unroll
    for (int ks = 0; ks < 2; ++ks) {
      int row = wrow + l15;
      bhalf8 va = *(const bhalf8*)&Vs[(row<<6) + ((((ks<<2)+quad) ^ (row&7))<<3)];
      bhalf8 aw;
#pragma unroll
      for (int i = 0; i < 8; ++i) aw[i] = f2bf(bf2f(va[i]) * wgt[ks*8 + i]);
      bhalf8 bk[4];
#pragma unroll
      for (int ct = 0; ct < 4; ++ct) {
        int kr = ct*16 + l15;
        bk[ct] = *(const bhalf8*)&Ks[(kr<<6) + ((((ks<<2)+quad) ^ (kr&7))<<3)];
      }
#pragma unroll
      for (int ct = 0; ct < 4; ++ct)
        acc[ct] = __builtin_amdgcn_mfma_f32_16x16x32_bf16(aw, bk[ct], acc[ct], 0, 0, 0);
    }
  }
  size_t base = (size_t)(bh*4 + p) * 2 * 4096;
#pragma unroll
  for (int ct = 0; ct < 4; ++ct)
#pragma unroll
    for (int r = 0; r < 4; ++r) {
      int e = wrow + (quad<<2) + r, d = ct*16 + l15;
      float x = acc[ct][r];
      short hi = f2bf(x);
      short lo = f2bf(x - bf2f(hi));
      Pseg[base + e*64 + d]        = hi;
      Pseg[base + 4096 + e*64 + d] = lo;
    }
}

// Chunked retention: grid 1024 uniform blocks = (bh, chunk).
__global__ __launch_bounds__(256) void retention_chunk(
    const short* __restrict__ Qb, const short* __restrict__ Kb,
    const short* __restrict__ Kt, const short* __restrict__ Vt,
    const short* __restrict__ Pseg,
    const float* __restrict__ gnw, const float* __restrict__ gnb,
    short* __restrict__ Xn)
{
  __shared__ __align__(16) short Vs[64*64];    // V^T [e][tok] (scan, then own)
  __shared__ __align__(16) short Kts[64*64];   // K^T [d][tok] (scan)
  __shared__ __align__(16) short KSs[64*64];   // K [tok][d], reused as Ss
  __shared__ __align__(16) short Sh[64*64];    // state hi [e][d]
  __shared__ __align__(16) short Sl[64*64];    // state lo [e][d]

  const int tid = threadIdx.x, lane = tid & 63, wv = tid >> 6;
  const int l15 = lane & 15, quad = lane >> 4;
  const int wrow = wv << 4;

  // idx -> (bh, c) with j varying among stride-256 siblings (CU balance)
  const int idx = blockIdx.x;
  const int bh = idx & 31;
  const int cc = idx >> 5;
  const int c  = ((cc & 7) << 2) | (cc >> 3);
  const int p = c >> 3, j = c & 7;
  const int b = bh >> 4, h = bh & 15;
  const int n0 = c << 6;

  const float log2g = log2f(1.f - exp2f(-5.f - (float)h));
  const float g64 = exp2f(log2g * 64.f);

  const short* Qg  = Qb + ((size_t)bh*T_ + n0 + wrow) * DH_;
  const short* Kg  = Kb + (size_t)bh*T_*DH_;
  const short* Ktg = Kt + (size_t)bh*DH_*T_;
  const short* Vtg = Vt + (size_t)bh*DH_*T_;

  bhalf8 aq[2];
#pragma unroll
  for (int ks = 0; ks < 2; ++ks)
    aq[ks] = *(const bhalf8*)(Qg + (size_t)l15*DH_ + ks*32 + quad*8);

  float rowf[4], colf0[4];
#pragma unroll
  for (int r = 0; r < 4; ++r)
    rowf[r] = exp2f(log2g * (float)(wrow + (quad<<2) + r)) * 0.125f;
#pragma unroll
  for (int ct = 0; ct < 4; ++ct)
    colf0[ct] = exp2f(-log2g * (float)(ct*16 + l15));

  const bool has_state = (c > 0);

  // ---- state scan over own-segment chunks 0..j-1 ----
  floatx4 st[4] = {};
  if (j > 0) {
    float wgt[16];
#pragma unroll
    for (int ks = 0; ks < 2; ++ks)
#pragma unroll
      for (int i = 0; i < 8; ++i)
        wgt[ks*8 + i] = exp2f(log2g * (float)(64 - (ks*32 + (quad<<3) + i)));
    for (int jp = 0; jp < j; ++jp) {
      if (log2g * (float)((j - 1 - jp) << 6) < -34.f) continue; // fully decayed
      const int m0 = ((p<<3) + jp) << 6;
      __syncthreads();
#pragma unroll
      for (int i = 0; i < 2; ++i) {
        int slot = (i<<8) + tid;
        int r = slot >> 3, g = (slot & 7) ^ (r & 7);
        gll16(&Kts[((i<<8) + (wv<<6))*8], Ktg + (size_t)r*T_ + m0 + (g<<3));
        gll16(&Vs[((i<<8) + (wv<<6))*8],  Vtg + (size_t)r*T_ + m0 + (g<<3));
      }
      __syncthreads();
#pragma unroll
      for (int ct = 0; ct < 4; ++ct)
#pragma unroll
        for (int r = 0; r < 4; ++r) st[ct][r] *= g64;
#pragma unroll
      for (int ks = 0; ks < 2; ++ks) {
        int row = wrow + l15;
        bhalf8 va = *(const bhalf8*)&Vs[(row<<6) + ((((ks<<2)+quad) ^ (row&7))<<3)];
        bhalf8 aw;
#pragma unroll
        for (int i = 0; i < 8; ++i) aw[i] = f2bf(bf2f(va[i]) * wgt[ks*8 + i]);
        bhalf8 bk[4];
#pragma unroll
        for (int ct = 0; ct < 4; ++ct) {
          int kr = ct*16 + l15;
          bk[ct] = *(const bhalf8*)&Kts[(kr<<6) + ((((ks<<2)+quad) ^ (kr&7))<<3)];
        }
#pragma unroll
        for (int ct = 0; ct < 4; ++ct)
          st[ct] = __builtin_amdgcn_mfma_f32_16x16x32_bf16(aw, bk[ct], st[ct], 0, 0, 0);
      }
    }
  }
  // ---- add weighted previous-segment summaries ----
  for (int pp = 0; pp < p; ++pp) {
    float wexp = log2g * (float)(n0 - ((pp + 1) << 9));
    if (wexp < -34.f) continue;
    float w = exp2f(wexp);
    const short* Pg = Pseg + (size_t)(bh*4 + pp) * 2 * 4096;
#pragma unroll
    for (int ct = 0; ct < 4; ++ct)
#pragma unroll
      for (int r = 0; r < 4; ++r) {
        int e = wrow + (quad<<2) + r, d = ct*16 + l15;
        st[ct][r] += w * (bf2f(Pg[e*64 + d]) + bf2f(Pg[4096 + e*64 + d]));
      }
  }
  // ---- split state to bf16 hi/lo in LDS ----
  if (has_state) {
#pragma unroll
    for (int ct = 0; ct < 4; ++ct)
#pragma unroll
      for (int r = 0; r < 4; ++r) {
        int e = wrow + (quad<<2) + r, d = ct*16 + l15;
        float x = st[ct][r];
        short hi = f2bf(x);
        short lo = f2bf(x - bf2f(hi));
        int addr = (e<<6) + ((((d>>3) ^ (e&7))<<3)) + (d&7);
        Sh[addr] = hi; Sl[addr] = lo;
      }
  }

  // ---- stage own chunk: K token-major + V^T ----
  __syncthreads();                     // covers Sh/Sl writes + frees Vs/Kts
#pragma unroll
  for (int i = 0; i < 2; ++i) {
    int slot = (i<<8) + tid;
    int r = slot >> 3, g = (slot & 7) ^ (r & 7);
    gll16(&KSs[((i<<8) + (wv<<6))*8], Kg  + (size_t)(n0 + r)*DH_ + (g<<3));
    gll16(&Vs[((i<<8) + (wv<<6))*8],  Vtg + (size_t)r*T_ + n0 + (g<<3));
  }
  __syncthreads();

  // ---- intra: QK^T on diagonal chunk ----
  floatx4 sacc[4] = {};
#pragma unroll
  for (int ks = 0; ks < 2; ++ks) {
    bhalf8 bk[4];
#pragma unroll
    for (int ct = 0; ct < 4; ++ct) {
      int row = ct*16 + l15;
      bk[ct] = *(const bhalf8*)&KSs[(row<<6) + ((((ks<<2)+quad) ^ (row&7))<<3)];
    }
#pragma unroll
    for (int ct = 0; ct < 4; ++ct)
      sacc[ct] = __builtin_amdgcn_mfma_f32_16x16x32_bf16(aq[ks], bk[ct], sacc[ct], 0, 0, 0);
  }
  __syncthreads();                     // all waves done reading KSs -> reuse as Ss
#pragma unroll
  for (int ct = 0; ct < 4; ++ct) {
    float cf = colf0[ct];
    int colg = (ct<<1) + (l15>>3);
    int m = ct*16 + l15;
#pragma unroll
    for (int r = 0; r < 4; ++r) {
      int row = wrow + (quad<<2) + r;
      float v = (row >= m) ? sacc[ct][r] * (rowf[r] * cf) : 0.f;
      KSs[(row<<6) + ((colg ^ ((row>>1)&7))<<3) + (l15&7)] = f2bf(v);
    }
  }
  // no barrier: wave reads back only its own Ss rows
  floatx4 oacc[4] = {};
#pragma unroll
  for (int ks = 0; ks < 2; ++ks) {
    int row = wrow + l15;
    bhalf8 as_ = *(const bhalf8*)&KSs[(row<<6) + ((((ks<<2)+quad) ^ ((row>>1)&7))<<3)];
    bhalf8 bv[4];
#pragma unroll
    for (int ct = 0; ct < 4; ++ct) {
      int vrow = ct*16 + l15;
      bv[ct] = *(const bhalf8*)&Vs[(vrow<<6) + ((((ks<<2)+quad) ^ (vrow&7))<<3)];
    }
#pragma unroll
    for (int ct = 0; ct < 4; ++ct)
      oacc[ct] = __builtin_amdgcn_mfma_f32_16x16x32_bf16(as_, bv[ct], oacc[ct], 0, 0, 0);
  }

  // ---- inter: O += gamma^i/8 * Q @ St ----
  if (has_state) {
    floatx4 iacc[4] = {};
#pragma unroll
    for (int ks = 0; ks < 2; ++ks) {
      bhalf8 bhf[4], blf[4];
#pragma unroll
      for (int ct = 0; ct < 4; ++ct) {
        int er = ct*16 + l15;
        int ga = ((((ks<<2)+quad) ^ (er&7))<<3);
        bhf[ct] = *(const bhalf8*)&Sh[(er<<6) + ga];
        blf[ct] = *(const bhalf8*)&Sl[(er<<6) + ga];
      }
#pragma unroll
      for (int ct = 0; ct < 4; ++ct) {
        iacc[ct] = __builtin_amdgcn_mfma_f32_16x16x32_bf16(aq[ks], bhf[ct], iacc[ct], 0, 0, 0);
        iacc[ct] = __builtin_amdgcn_mfma_f32_16x16x32_bf16(aq[ks], blf[ct], iacc[ct], 0, 0, 0);
      }
    }
#pragma unroll
    for (int ct = 0; ct < 4; ++ct)
#pragma unroll
      for (int r = 0; r < 4; ++r)
        oacc[ct][r] += rowf[r] * iacc[ct][r];
  }

  // ---- fused GroupNorm over DH, write (B,T,C) bf16 ----
#pragma unroll
  for (int r = 0; r < 4; ++r) {
    float s1 = oacc[0][r] + oacc[1][r] + oacc[2][r] + oacc[3][r];
    float s2 = oacc[0][r]*oacc[0][r] + oacc[1][r]*oacc[1][r]
             + oacc[2][r]*oacc[2][r] + oacc[3][r]*oacc[3][r];
#pragma unroll
    for (int off = 1; off < 16; off <<= 1) {
      s1 += __shfl_xor(s1, off);
      s2 += __shfl_xor(s2, off);
    }
    float mean = s1 * (1.f/64.f);
    float var  = s2 * (1.f/64.f) - mean*mean;
    float rstd = rsqrtf(var + 1e-5f);
    int t = n0 + wrow + (quad<<2) + r;
    size_t obase = ((size_t)b*T_ + t)*C_ + h*DH_;
#pragma unroll
    for (int ct = 0; ct < 4; ++ct) {
      int d = ct*16 + l15;
      float y = (oacc[ct][r] - mean)*rstd*gnw[h*DH_ + d] + gnb[h*DH_ + d];
      Xn[obase + d] = f2bf(y);
    }
  }
}

extern "C" void kernel_launch(void* const* d_in, const int* in_sizes, int n_in,
                              void* d_out, int out_size, void* d_ws, size_t ws_size,
                              hipStream_t stream) {
  (void)in_sizes; (void)n_in; (void)out_size; (void)ws_size;
  const float* x   = (const float*)d_in[0];
  const float* Wq  = (const float*)d_in[1];
  const float* Wk  = (const float*)d_in[2];
  const float* Wv  = (const float*)d_in[3];
  const float* Wo  = (const float*)d_in[4];
  const float* gnw = (const float*)d_in[5];
  const float* gnb = (const float*)d_in[6];
  float* out = (float*)d_out;

  char* ws = (char*)d_ws;                 // 48 MB total
  short* Xb   = (short*)(ws);             // [0,8): x bf16; reused as Ktb after qkv
  short* Ktb  = (short*)(ws);             //   K^T (B,H,DH,T)
  short* Wqb  = (short*)(ws + (8u<<20));  // [8,10): Wq bf16; reused as Pseg
  short* Pseg = (short*)(ws + (8u<<20));  //   segment states, 2 MB
  short* Wkb  = (short*)(ws + (10u<<20));
  short* Wvb  = (short*)(ws + (12u<<20));
  short* Wob  = (short*)(ws + (14u<<20));
  short* Qb   = (short*)(ws + (16u<<20)); // (B,H,T,DH)
  short* Kb   = (short*)(ws + (24u<<20)); // (B,H,T,DH)
  short* Vtw  = (short*)(ws + (32u<<20)); // V^T (B,H,DH,T)
  short* Xn   = (short*)(ws + (40u<<20)); // retention out (B,T,C) bf16

  cvt_all<<<(M_*C_/4 + 4*(C_*C_/4)) / 256, 256, 0, stream>>>(
      x, Wq, Wk, Wv, Wo, Xb, Wqb, Wkb, Wvb, Wob);

  gemm_qkv<<<dim3(24, 32), 256, 0, stream>>>(Xb, Wqb, Wkb, Wvb, Qb, Kb, Vtw);
  transpose_k<<<1024, 256, 0, stream>>>(Kb, Ktb);
  seg_state<<<128, 256, 0, stream>>>(Ktb, Vtw, Pseg);
  retention_chunk<<<1024, 256, 0, stream>>>(Qb, Kb, Ktb, Vtw, Pseg, gnw, gnb, Xn);
  gemm_out<<<dim3(16, 32), 256, 0, stream>>>(Xn, Wob, out);
}

// Round 8
// 183.649 us; speedup vs baseline: 1.9955x; 1.0213x over previous
//
#include <hip/hip_runtime.h>
#include <stdint.h>

#define B_ 2
#define T_ 2048
#define C_ 1024
#define H_ 16
#define DH_ 64
#define M_ (B_*T_)   // 4096

typedef short bhalf8 __attribute__((ext_vector_type(8)));
typedef float floatx4 __attribute__((ext_vector_type(4)));

__device__ __forceinline__ short f2bf(float f) {
  unsigned u = __float_as_uint(f);
  u += 0x7fffu + ((u >> 16) & 1u);   // round-to-nearest-even
  return (short)(u >> 16);
}
__device__ __forceinline__ float bf2f(short s) {
  return __uint_as_float(((unsigned)(unsigned short)s) << 16);
}

// async global->LDS, 16B per lane; lds_dst wave-uniform (lane -> +lane*16)
__device__ __forceinline__ void gll16(void* lds_dst, const void* g_src) {
  __builtin_amdgcn_global_load_lds(
      reinterpret_cast<const uint32_t __attribute__((address_space(1)))*>(
          reinterpret_cast<uintptr_t>(g_src)),
      reinterpret_cast<uint32_t __attribute__((address_space(3)))*>(
          reinterpret_cast<uintptr_t>(lds_dst)),
      16, 0, 0);
}

__global__ void cvt_all(
    const float* __restrict__ x,  const float* __restrict__ wq,
    const float* __restrict__ wk, const float* __restrict__ wv,
    const float* __restrict__ wo,
    short* __restrict__ xb, short* __restrict__ wqb, short* __restrict__ wkb,
    short* __restrict__ wvb, short* __restrict__ wob)
{
  int i = blockIdx.x * blockDim.x + threadIdx.x;
  const float* s; short* d; int off;
  if (i < (M_*C_/4)) { s = x; d = xb; off = i; }
  else {
    int j = i - M_*C_/4;
    int w = j >> 18;                     // C_*C_/4 == 1<<18
    off = j & ((1<<18) - 1);
    s = (w==0) ? wq : (w==1) ? wk : (w==2) ? wv : wo;
    d = (w==0) ? wqb : (w==1) ? wkb : (w==2) ? wvb : wob;
  }
  float4 v = ((const float4*)s)[off];
  short4 o;
  o.x = f2bf(v.x); o.y = f2bf(v.y); o.z = f2bf(v.z); o.w = f2bf(v.w);
  ((short4*)d)[off] = o;
}

// Fused Q/K/V projection. Grid (24,32): x<8 -> Q, x<16 -> K, x>=16 -> V
// (operands swapped so C/D layout gives coalesced V^T store).
// R8: BK=64 + XOR-swizzled LDS (R7 had linear layout -> 3.1M conflict cycles,
// 8-way ds_read_b128 conflicts; swizzle makes it 2-way = free), halves barriers.
__global__ __launch_bounds__(256) void gemm_qkv(
    const short* __restrict__ X,
    const short* __restrict__ Wq, const short* __restrict__ Wk, const short* __restrict__ Wv,
    short* __restrict__ Qb, short* __restrict__ Kb, short* __restrict__ Vt)
{
  __shared__ __align__(16) short As[128*64];   // swizzled: granule g at g^(row&7)
  __shared__ __align__(16) short Bs[128*64];
  const int tid  = threadIdx.x;
  const int lane = tid & 63;
  const int wv   = tid >> 6;
  const int l15  = lane & 15;
  const int quad = lane >> 4;
  const int wm   = (wv >> 1) << 6;
  const int wn   = (wv & 1) << 6;
  const int nx   = blockIdx.x;
  const int m0   = blockIdx.y << 7;
  const int K    = C_;

  const short *Ab, *Bb;
  int nloc, kind;                    // 0=Q 1=K 2=V
  if (nx < 8)       { kind = 0; nloc = nx << 7;        Ab = X  + (size_t)m0*K;   Bb = Wq + (size_t)nloc*K; }
  else if (nx < 16) { kind = 1; nloc = (nx - 8) << 7;  Ab = X  + (size_t)m0*K;   Bb = Wk + (size_t)nloc*K; }
  else              { kind = 2; nloc = (nx - 16) << 7; Ab = Wv + (size_t)nloc*K; Bb = X  + (size_t)m0*K;   }

  floatx4 acc[4][4] = {};

  for (int k0 = 0; k0 < K; k0 += 64) {
    __syncthreads();                     // LDS reuse guard
#pragma unroll
    for (int i = 0; i < 4; ++i) {        // 1024 chunks of 16B per 128x64 tile
      int c = (i<<8) + tid, r = c >> 3, g = (c & 7) ^ (r & 7);
      gll16(&As[((i<<8) + (wv<<6))*8], Ab + (size_t)r*K + k0 + (g<<3));
      gll16(&Bs[((i<<8) + (wv<<6))*8], Bb + (size_t)r*K + k0 + (g<<3));
    }
    __syncthreads();                     // vmcnt drain at barrier
#pragma unroll
    for (int ks = 0; ks < 2; ++ks) {
      bhalf8 af[4], bfr[4];
#pragma unroll
      for (int rt = 0; rt < 4; ++rt) {
        int row = wm + rt*16 + l15;
        af[rt] = *(const bhalf8*)&As[(row<<6) + ((((ks<<2)+quad) ^ (row&7))<<3)];
      }
#pragma unroll
      for (int ct = 0; ct < 4; ++ct) {
        int row = wn + ct*16 + l15;
        bfr[ct] = *(const bhalf8*)&Bs[(row<<6) + ((((ks<<2)+quad) ^ (row&7))<<3)];
      }
#pragma unroll
      for (int rt = 0; rt < 4; ++rt)
#pragma unroll
        for (int ct = 0; ct < 4; ++ct)
          acc[rt][ct] = __builtin_amdgcn_mfma_f32_16x16x32_bf16(af[rt], bfr[ct], acc[rt][ct], 0, 0, 0);
    }
  }

  if (kind < 2) {                        // Q or K: RoPE epilogue -> (B,H,T,DH)
    short* Cb = kind ? Kb : Qb;
    const int hh = (nloc + wn) >> 6;
#pragma unroll
    for (int rt = 0; rt < 4; ++rt)
#pragma unroll
      for (int r = 0; r < 4; ++r) {
        int n  = m0 + wm + rt*16 + quad*4 + r;
        int bb = n >> 11, t = n & (T_-1);
        size_t base = ((size_t)(bb*H_ + hh)*T_ + t)*DH_;
        float tf = (float)t;
#pragma unroll
        for (int ct = 0; ct < 2; ++ct) {
          int ii = ct*16 + l15;
          float ang = tf * exp2f((float)ii * (-0.4152410118609203f));
          float sn = __sinf(ang), cs = __cosf(ang);
          float xlo = acc[rt][ct][r], xhi = acc[rt][ct+2][r];
          Cb[base + ii]      = f2bf(xlo*cs - xhi*sn);
          Cb[base + ii + 32] = f2bf(xhi*cs + xlo*sn);
        }
      }
  } else {                               // V: rows=channels, cols=tokens -> V^T
#pragma unroll
    for (int rt = 0; rt < 4; ++rt)
#pragma unroll
      for (int r = 0; r < 4; ++r) {
        int o = nloc + wm + rt*16 + quad*4 + r;
#pragma unroll
        for (int ct = 0; ct < 4; ++ct) {
          int n  = m0 + wn + ct*16 + l15;
          int bb = n >> 11, t = n & (T_-1);
          Vt[(size_t)bb*(C_*T_) + (size_t)o*T_ + t] = f2bf(acc[rt][ct][r]);
        }
      }
  }
}

// Final projection.
__global__ __launch_bounds__(256) void gemm_out(
    const short* __restrict__ A, const short* __restrict__ Bm, float* __restrict__ Cf)
{
  __shared__ __align__(16) short As[128*64];
  __shared__ __align__(16) short Bs[64*64];
  const int tid = threadIdx.x, lane = tid & 63, wv = tid >> 6;
  const int l15 = lane & 15, quad = lane >> 4;
  const int n0 = blockIdx.x << 6;
  const int m0 = blockIdx.y << 7;

  floatx4 acc[2][4] = {};
  const short* Ab = A  + (size_t)m0 * C_;
  const short* Bb = Bm + (size_t)n0 * C_;

  for (int k0 = 0; k0 < C_; k0 += 64) {
    __syncthreads();
#pragma unroll
    for (int i = 0; i < 4; ++i) {
      int c = (i<<8) + tid, r = c >> 3, g = (c & 7) ^ (r & 7);
      gll16(&As[((i<<8) + (wv<<6))*8], Ab + (size_t)r*C_ + k0 + (g<<3));
    }
#pragma unroll
    for (int i = 0; i < 2; ++i) {
      int c = (i<<8) + tid, r = c >> 3, g = (c & 7) ^ (r & 7);
      gll16(&Bs[((i<<8) + (wv<<6))*8], Bb + (size_t)r*C_ + k0 + (g<<3));
    }
    __syncthreads();
#pragma unroll
    for (int ks = 0; ks < 2; ++ks) {
      bhalf8 af[2], bfr[4];
#pragma unroll
      for (int rt = 0; rt < 2; ++rt) {
        int row = (wv<<5) + rt*16 + l15;
        af[rt] = *(const bhalf8*)&As[(row<<6) + ((((ks<<2)+quad) ^ (row&7))<<3)];
      }
#pragma unroll
      for (int ct = 0; ct < 4; ++ct) {
        int row = ct*16 + l15;
        bfr[ct] = *(const bhalf8*)&Bs[(row<<6) + ((((ks<<2)+quad) ^ (row&7))<<3)];
      }
#pragma unroll
      for (int rt = 0; rt < 2; ++rt)
#pragma unroll
        for (int ct = 0; ct < 4; ++ct)
          acc[rt][ct] = __builtin_amdgcn_mfma_f32_16x16x32_bf16(af[rt], bfr[ct], acc[rt][ct], 0, 0, 0);
    }
  }

#pragma unroll
  for (int rt = 0; rt < 2; ++rt)
#pragma unroll
    for (int r = 0; r < 4; ++r) {
      int n = m0 + (wv<<5) + rt*16 + quad*4 + r;
#pragma unroll
      for (int ct = 0; ct < 4; ++ct)
        Cf[(size_t)n * C_ + n0 + ct*16 + l15] = acc[rt][ct][r];
    }
}

// K (B,H,T,DH) -> Kt (B,H,DH,T). Grid 1024 = bh*32 + token-chunk.
__global__ __launch_bounds__(256) void transpose_k(
    const short* __restrict__ Kb, short* __restrict__ Kt)
{
  __shared__ short tile[64*66];
  const int idx = blockIdx.x, bh = idx >> 5, tc = idx & 31;
  const int t0 = tc << 6;
  const short* src = Kb + ((size_t)bh*T_ + t0) * DH_;
  int row = threadIdx.x >> 2, c0 = (threadIdx.x & 3) << 4;
  *(int4*)&tile[row*66 + c0]     = *(const int4*)&src[row*64 + c0];
  *(int4*)&tile[row*66 + c0 + 8] = *(const int4*)&src[row*64 + c0 + 8];
  __syncthreads();
  short* dst = Kt + (size_t)bh*DH_*T_;
  int d = threadIdx.x >> 2, k0 = (threadIdx.x & 3) << 4;
  short tmp[16];
#pragma unroll
  for (int i = 0; i < 16; ++i) tmp[i] = tile[(k0 + i)*66 + d];
  *(int4*)&dst[(size_t)d*T_ + t0 + k0]     = *(const int4*)&tmp[0];
  *(int4*)&dst[(size_t)d*T_ + t0 + k0 + 8] = *(const int4*)&tmp[8];
}

// Per-segment state summaries. Grid 128 = bh*4 + p.
__global__ __launch_bounds__(256) void seg_state(
    const short* __restrict__ Kt, const short* __restrict__ Vt,
    short* __restrict__ Pseg)
{
  __shared__ __align__(16) short Ks[64*64];   // K^T [d][tok], swizzled
  __shared__ __align__(16) short Vs[64*64];   // V^T [e][tok], swizzled
  const int tid = threadIdx.x, lane = tid & 63, wv = tid >> 6;
  const int l15 = lane & 15, quad = lane >> 4;
  const int wrow = wv << 4;
  const int bh = blockIdx.x >> 2, p = blockIdx.x & 3;
  const int h = bh & 15;
  const float log2g = log2f(1.f - exp2f(-5.f - (float)h));
  const float g64 = exp2f(log2g * 64.f);

  float wgt[16];
#pragma unroll
  for (int ks = 0; ks < 2; ++ks)
#pragma unroll
    for (int i = 0; i < 8; ++i)
      wgt[ks*8 + i] = exp2f(log2g * (float)(64 - (ks*32 + (quad<<3) + i)));

  const short* Ktg = Kt + (size_t)bh*DH_*T_;
  const short* Vtg = Vt + (size_t)bh*DH_*T_;

  floatx4 acc[4] = {};
  for (int j = 0; j < 8; ++j) {
    const int m0 = ((p<<3) + j) << 6;
    __syncthreads();
#pragma unroll
    for (int i = 0; i < 2; ++i) {
      int slot = (i<<8) + tid;
      int r = slot >> 3, g = (slot & 7) ^ (r & 7);
      gll16(&Ks[((i<<8) + (wv<<6))*8], Ktg + (size_t)r*T_ + m0 + (g<<3));
      gll16(&Vs[((i<<8) + (wv<<6))*8], Vtg + (size_t)r*T_ + m0 + (g<<3));
    }
    __syncthreads();
#pragma unroll
    for (int ct = 0; ct < 4; ++ct)
#pragma unroll
      for (int r = 0; r < 4; ++r) acc[ct][r] *= g64;
#pragma unroll
    for (int ks = 0; ks < 2; ++ks) {
      int row = wrow + l15;
      bhalf8 va = *(const bhalf8*)&Vs[(row<<6) + ((((ks<<2)+quad) ^ (row&7))<<3)];
      bhalf8 aw;
#pragma unroll
      for (int i = 0; i < 8; ++i) aw[i] = f2bf(bf2f(va[i]) * wgt[ks*8 + i]);
      bhalf8 bk[4];
#pragma unroll
      for (int ct = 0; ct < 4; ++ct) {
        int kr = ct*16 + l15;
        bk[ct] = *(const bhalf8*)&Ks[(kr<<6) + ((((ks<<2)+quad) ^ (kr&7))<<3)];
      }
#pragma unroll
      for (int ct = 0; ct < 4; ++ct)
        acc[ct] = __builtin_amdgcn_mfma_f32_16x16x32_bf16(aw, bk[ct], acc[ct], 0, 0, 0);
    }
  }
  size_t base = (size_t)(bh*4 + p) * 2 * 4096;
#pragma unroll
  for (int ct = 0; ct < 4; ++ct)
#pragma unroll
    for (int r = 0; r < 4; ++r) {
      int e = wrow + (quad<<2) + r, d = ct*16 + l15;
      float x = acc[ct][r];
      short hi = f2bf(x);
      short lo = f2bf(x - bf2f(hi));
      Pseg[base + e*64 + d]        = hi;
      Pseg[base + 4096 + e*64 + d] = lo;
    }
}

// Chunked retention: grid 1024 uniform blocks = (bh, chunk).
__global__ __launch_bounds__(256) void retention_chunk(
    const short* __restrict__ Qb, const short* __restrict__ Kb,
    const short* __restrict__ Kt, const short* __restrict__ Vt,
    const short* __restrict__ Pseg,
    const float* __restrict__ gnw, const float* __restrict__ gnb,
    short* __restrict__ Xn)
{
  __shared__ __align__(16) short Vs[64*64];    // V^T [e][tok] (scan, then own)
  __shared__ __align__(16) short Kts[64*64];   // K^T [d][tok] (scan)
  __shared__ __align__(16) short KSs[64*64];   // K [tok][d], reused as Ss
  __shared__ __align__(16) short Sh[64*64];    // state hi [e][d]
  __shared__ __align__(16) short Sl[64*64];    // state lo [e][d]

  const int tid = threadIdx.x, lane = tid & 63, wv = tid >> 6;
  const int l15 = lane & 15, quad = lane >> 4;
  const int wrow = wv << 4;

  // idx -> (bh, c) with j varying among stride-256 siblings (CU balance)
  const int idx = blockIdx.x;
  const int bh = idx & 31;
  const int cc = idx >> 5;
  const int c  = ((cc & 7) << 2) | (cc >> 3);
  const int p = c >> 3, j = c & 7;
  const int b = bh >> 4, h = bh & 15;
  const int n0 = c << 6;

  const float log2g = log2f(1.f - exp2f(-5.f - (float)h));
  const float g64 = exp2f(log2g * 64.f);

  const short* Qg  = Qb + ((size_t)bh*T_ + n0 + wrow) * DH_;
  const short* Kg  = Kb + (size_t)bh*T_*DH_;
  const short* Ktg = Kt + (size_t)bh*DH_*T_;
  const short* Vtg = Vt + (size_t)bh*DH_*T_;

  bhalf8 aq[2];
#pragma unroll
  for (int ks = 0; ks < 2; ++ks)
    aq[ks] = *(const bhalf8*)(Qg + (size_t)l15*DH_ + ks*32 + quad*8);

  float rowf[4], colf0[4];
#pragma unroll
  for (int r = 0; r < 4; ++r)
    rowf[r] = exp2f(log2g * (float)(wrow + (quad<<2) + r)) * 0.125f;
#pragma unroll
  for (int ct = 0; ct < 4; ++ct)
    colf0[ct] = exp2f(-log2g * (float)(ct*16 + l15));

  const bool has_state = (c > 0);

  // ---- state scan over own-segment chunks 0..j-1 ----
  floatx4 st[4] = {};
  if (j > 0) {
    float wgt[16];
#pragma unroll
    for (int ks = 0; ks < 2; ++ks)
#pragma unroll
      for (int i = 0; i < 8; ++i)
        wgt[ks*8 + i] = exp2f(log2g * (float)(64 - (ks*32 + (quad<<3) + i)));
    for (int jp = 0; jp < j; ++jp) {
      if (log2g * (float)((j - 1 - jp) << 6) < -34.f) continue; // fully decayed
      const int m0 = ((p<<3) + jp) << 6;
      __syncthreads();
#pragma unroll
      for (int i = 0; i < 2; ++i) {
        int slot = (i<<8) + tid;
        int r = slot >> 3, g = (slot & 7) ^ (r & 7);
        gll16(&Kts[((i<<8) + (wv<<6))*8], Ktg + (size_t)r*T_ + m0 + (g<<3));
        gll16(&Vs[((i<<8) + (wv<<6))*8],  Vtg + (size_t)r*T_ + m0 + (g<<3));
      }
      __syncthreads();
#pragma unroll
      for (int ct = 0; ct < 4; ++ct)
#pragma unroll
        for (int r = 0; r < 4; ++r) st[ct][r] *= g64;
#pragma unroll
      for (int ks = 0; ks < 2; ++ks) {
        int row = wrow + l15;
        bhalf8 va = *(const bhalf8*)&Vs[(row<<6) + ((((ks<<2)+quad) ^ (row&7))<<3)];
        bhalf8 aw;
#pragma unroll
        for (int i = 0; i < 8; ++i) aw[i] = f2bf(bf2f(va[i]) * wgt[ks*8 + i]);
        bhalf8 bk[4];
#pragma unroll
        for (int ct = 0; ct < 4; ++ct) {
          int kr = ct*16 + l15;
          bk[ct] = *(const bhalf8*)&Kts[(kr<<6) + ((((ks<<2)+quad) ^ (kr&7))<<3)];
        }
#pragma unroll
        for (int ct = 0; ct < 4; ++ct)
          st[ct] = __builtin_amdgcn_mfma_f32_16x16x32_bf16(aw, bk[ct], st[ct], 0, 0, 0);
      }
    }
  }
  // ---- add weighted previous-segment summaries ----
  for (int pp = 0; pp < p; ++pp) {
    float wexp = log2g * (float)(n0 - ((pp + 1) << 9));
    if (wexp < -34.f) continue;
    float w = exp2f(wexp);
    const short* Pg = Pseg + (size_t)(bh*4 + pp) * 2 * 4096;
#pragma unroll
    for (int ct = 0; ct < 4; ++ct)
#pragma unroll
      for (int r = 0; r < 4; ++r) {
        int e = wrow + (quad<<2) + r, d = ct*16 + l15;
        st[ct][r] += w * (bf2f(Pg[e*64 + d]) + bf2f(Pg[4096 + e*64 + d]));
      }
  }
  // ---- split state to bf16 hi/lo in LDS ----
  if (has_state) {
#pragma unroll
    for (int ct = 0; ct < 4; ++ct)
#pragma unroll
      for (int r = 0; r < 4; ++r) {
        int e = wrow + (quad<<2) + r, d = ct*16 + l15;
        float x = st[ct][r];
        short hi = f2bf(x);
        short lo = f2bf(x - bf2f(hi));
        int addr = (e<<6) + ((((d>>3) ^ (e&7))<<3)) + (d&7);
        Sh[addr] = hi; Sl[addr] = lo;
      }
  }

  // ---- stage own chunk: K token-major + V^T ----
  __syncthreads();                     // covers Sh/Sl writes + frees Vs/Kts
#pragma unroll
  for (int i = 0; i < 2; ++i) {
    int slot = (i<<8) + tid;
    int r = slot >> 3, g = (slot & 7) ^ (r & 7);
    gll16(&KSs[((i<<8) + (wv<<6))*8], Kg  + (size_t)(n0 + r)*DH_ + (g<<3));
    gll16(&Vs[((i<<8) + (wv<<6))*8],  Vtg + (size_t)r*T_ + n0 + (g<<3));
  }
  __syncthreads();

  // ---- intra: QK^T on diagonal chunk ----
  floatx4 sacc[4] = {};
#pragma unroll
  for (int ks = 0; ks < 2; ++ks) {
    bhalf8 bk[4];
#pragma unroll
    for (int ct = 0; ct < 4; ++ct) {
      int row = ct*16 + l15;
      bk[ct] = *(const bhalf8*)&KSs[(row<<6) + ((((ks<<2)+quad) ^ (row&7))<<3)];
    }
#pragma unroll
    for (int ct = 0; ct < 4; ++ct)
      sacc[ct] = __builtin_amdgcn_mfma_f32_16x16x32_bf16(aq[ks], bk[ct], sacc[ct], 0, 0, 0);
  }
  __syncthreads();                     // all waves done reading KSs -> reuse as Ss
#pragma unroll
  for (int ct = 0; ct < 4; ++ct) {
    float cf = colf0[ct];
    int colg = (ct<<1) + (l15>>3);
    int m = ct*16 + l15;
#pragma unroll
    for (int r = 0; r < 4; ++r) {
      int row = wrow + (quad<<2) + r;
      float v = (row >= m) ? sacc[ct][r] * (rowf[r] * cf) : 0.f;
      KSs[(row<<6) + ((colg ^ ((row>>1)&7))<<3) + (l15&7)] = f2bf(v);
    }
  }
  // no barrier: wave reads back only its own Ss rows
  floatx4 oacc[4] = {};
#pragma unroll
  for (int ks = 0; ks < 2; ++ks) {
    int row = wrow + l15;
    bhalf8 as_ = *(const bhalf8*)&KSs[(row<<6) + ((((ks<<2)+quad) ^ ((row>>1)&7))<<3)];
    bhalf8 bv[4];
#pragma unroll
    for (int ct = 0; ct < 4; ++ct) {
      int vrow = ct*16 + l15;
      bv[ct] = *(const bhalf8*)&Vs[(vrow<<6) + ((((ks<<2)+quad) ^ (vrow&7))<<3)];
    }
#pragma unroll
    for (int ct = 0; ct < 4; ++ct)
      oacc[ct] = __builtin_amdgcn_mfma_f32_16x16x32_bf16(as_, bv[ct], oacc[ct], 0, 0, 0);
  }

  // ---- inter: O += gamma^i/8 * Q @ St ----
  if (has_state) {
    floatx4 iacc[4] = {};
#pragma unroll
    for (int ks = 0; ks < 2; ++ks) {
      bhalf8 bhf[4], blf[4];
#pragma unroll
      for (int ct = 0; ct < 4; ++ct) {
        int er = ct*16 + l15;
        int ga = ((((ks<<2)+quad) ^ (er&7))<<3);
        bhf[ct] = *(const bhalf8*)&Sh[(er<<6) + ga];
        blf[ct] = *(const bhalf8*)&Sl[(er<<6) + ga];
      }
#pragma unroll
      for (int ct = 0; ct < 4; ++ct) {
        iacc[ct] = __builtin_amdgcn_mfma_f32_16x16x32_bf16(aq[ks], bhf[ct], iacc[ct], 0, 0, 0);
        iacc[ct] = __builtin_amdgcn_mfma_f32_16x16x32_bf16(aq[ks], blf[ct], iacc[ct], 0, 0, 0);
      }
    }
#pragma unroll
    for (int ct = 0; ct < 4; ++ct)
#pragma unroll
      for (int r = 0; r < 4; ++r)
        oacc[ct][r] += rowf[r] * iacc[ct][r];
  }

  // ---- fused GroupNorm over DH, write (B,T,C) bf16 ----
#pragma unroll
  for (int r = 0; r < 4; ++r) {
    float s1 = oacc[0][r] + oacc[1][r] + oacc[2][r] + oacc[3][r];
    float s2 = oacc[0][r]*oacc[0][r] + oacc[1][r]*oacc[1][r]
             + oacc[2][r]*oacc[2][r] + oacc[3][r]*oacc[3][r];
#pragma unroll
    for (int off = 1; off < 16; off <<= 1) {
      s1 += __shfl_xor(s1, off);
      s2 += __shfl_xor(s2, off);
    }
    float mean = s1 * (1.f/64.f);
    float var  = s2 * (1.f/64.f) - mean*mean;
    float rstd = rsqrtf(var + 1e-5f);
    int t = n0 + wrow + (quad<<2) + r;
    size_t obase = ((size_t)b*T_ + t)*C_ + h*DH_;
#pragma unroll
    for (int ct = 0; ct < 4; ++ct) {
      int d = ct*16 + l15;
      float y = (oacc[ct][r] - mean)*rstd*gnw[h*DH_ + d] + gnb[h*DH_ + d];
      Xn[obase + d] = f2bf(y);
    }
  }
}

extern "C" void kernel_launch(void* const* d_in, const int* in_sizes, int n_in,
                              void* d_out, int out_size, void* d_ws, size_t ws_size,
                              hipStream_t stream) {
  (void)in_sizes; (void)n_in; (void)out_size; (void)ws_size;
  const float* x   = (const float*)d_in[0];
  const float* Wq  = (const float*)d_in[1];
  const float* Wk  = (const float*)d_in[2];
  const float* Wv  = (const float*)d_in[3];
  const float* Wo  = (const float*)d_in[4];
  const float* gnw = (const float*)d_in[5];
  const float* gnb = (const float*)d_in[6];
  float* out = (float*)d_out;

  char* ws = (char*)d_ws;                 // 48 MB total
  short* Xb   = (short*)(ws);             // [0,8): x bf16; reused as Ktb after qkv
  short* Ktb  = (short*)(ws);             //   K^T (B,H,DH,T)
  short* Wqb  = (short*)(ws + (8u<<20));  // [8,10): Wq bf16; reused as Pseg
  short* Pseg = (short*)(ws + (8u<<20));  //   segment states, 2 MB
  short* Wkb  = (short*)(ws + (10u<<20));
  short* Wvb  = (short*)(ws + (12u<<20));
  short* Wob  = (short*)(ws + (14u<<20));
  short* Qb   = (short*)(ws + (16u<<20)); // (B,H,T,DH)
  short* Kb   = (short*)(ws + (24u<<20)); // (B,H,T,DH)
  short* Vtw  = (short*)(ws + (32u<<20)); // V^T (B,H,DH,T)
  short* Xn   = (short*)(ws + (40u<<20)); // retention out (B,T,C) bf16

  cvt_all<<<(M_*C_/4 + 4*(C_*C_/4)) / 256, 256, 0, stream>>>(
      x, Wq, Wk, Wv, Wo, Xb, Wqb, Wkb, Wvb, Wob);

  gemm_qkv<<<dim3(24, 32), 256, 0, stream>>>(Xb, Wqb, Wkb, Wvb, Qb, Kb, Vtw);
  transpose_k<<<1024, 256, 0, stream>>>(Kb, Ktb);
  seg_state<<<128, 256, 0, stream>>>(Ktb, Vtw, Pseg);
  retention_chunk<<<1024, 256, 0, stream>>>(Qb, Kb, Ktb, Vtw, Pseg, gnw, gnb, Xn);
  gemm_out<<<dim3(16, 32), 256, 0, stream>>>(Xn, Wob, out);
}

// Round 9
// 174.081 us; speedup vs baseline: 2.1052x; 1.0550x over previous
//
#include <hip/hip_runtime.h>
#include <stdint.h>

#define B_ 2
#define T_ 2048
#define C_ 1024
#define H_ 16
#define DH_ 64
#define M_ (B_*T_)   // 4096

typedef short bhalf8 __attribute__((ext_vector_type(8)));
typedef float floatx4 __attribute__((ext_vector_type(4)));

__device__ __forceinline__ short f2bf(float f) {
  unsigned u = __float_as_uint(f);
  u += 0x7fffu + ((u >> 16) & 1u);   // round-to-nearest-even
  return (short)(u >> 16);
}
__device__ __forceinline__ float bf2f(short s) {
  return __uint_as_float(((unsigned)(unsigned short)s) << 16);
}

// async global->LDS, 16B per lane; lds_dst wave-uniform (lane -> +lane*16)
__device__ __forceinline__ void gll16(void* lds_dst, const void* g_src) {
  __builtin_amdgcn_global_load_lds(
      reinterpret_cast<const uint32_t __attribute__((address_space(1)))*>(
          reinterpret_cast<uintptr_t>(g_src)),
      reinterpret_cast<uint32_t __attribute__((address_space(3)))*>(
          reinterpret_cast<uintptr_t>(lds_dst)),
      16, 0, 0);
}

__global__ void cvt_all(
    const float* __restrict__ x,  const float* __restrict__ wq,
    const float* __restrict__ wk, const float* __restrict__ wv,
    const float* __restrict__ wo,
    short* __restrict__ xb, short* __restrict__ wqb, short* __restrict__ wkb,
    short* __restrict__ wvb, short* __restrict__ wob)
{
  int i = blockIdx.x * blockDim.x + threadIdx.x;
  const float* s; short* d; int off;
  if (i < (M_*C_/4)) { s = x; d = xb; off = i; }
  else {
    int j = i - M_*C_/4;
    int w = j >> 18;                     // C_*C_/4 == 1<<18
    off = j & ((1<<18) - 1);
    s = (w==0) ? wq : (w==1) ? wk : (w==2) ? wv : wo;
    d = (w==0) ? wqb : (w==1) ? wkb : (w==2) ? wvb : wob;
  }
  float4 v = ((const float4*)s)[off];
  short4 o;
  o.x = f2bf(v.x); o.y = f2bf(v.y); o.z = f2bf(v.z); o.w = f2bf(v.w);
  ((short4*)d)[off] = o;
}

// Fused Q/K/V projection. Grid (24,32): x<8 -> Q, x<16 -> K, x>=16 -> V
// (operands swapped so C/D layout gives coalesced V^T store).
// R9: single-barrier double-buffered K-loop (BK=32): barrier; stage(next);
// compute(cur). vmcnt(0) drain at the NEXT barrier covers loads that had a
// full compute phase in flight -> stall ~0. Swizzle g^=(row>>1)&3 (2-way only).
__global__ __launch_bounds__(256) void gemm_qkv(
    const short* __restrict__ X,
    const short* __restrict__ Wq, const short* __restrict__ Wk, const short* __restrict__ Wv,
    short* __restrict__ Qb, short* __restrict__ Kb, short* __restrict__ Vt)
{
  __shared__ __align__(16) short As[2][128*32];   // 8 KB per buf
  __shared__ __align__(16) short Bs[2][128*32];
  const int tid  = threadIdx.x;
  const int lane = tid & 63;
  const int wv   = tid >> 6;
  const int l15  = lane & 15;
  const int quad = lane >> 4;
  const int wm   = (wv >> 1) << 6;
  const int wn   = (wv & 1) << 6;
  const int nx   = blockIdx.x;
  const int m0   = blockIdx.y << 7;
  const int K    = C_;

  const short *Ab, *Bb;
  int nloc, kind;                    // 0=Q 1=K 2=V
  if (nx < 8)       { kind = 0; nloc = nx << 7;        Ab = X  + (size_t)m0*K;   Bb = Wq + (size_t)nloc*K; }
  else if (nx < 16) { kind = 1; nloc = (nx - 8) << 7;  Ab = X  + (size_t)m0*K;   Bb = Wk + (size_t)nloc*K; }
  else              { kind = 2; nloc = (nx - 16) << 7; Ab = Wv + (size_t)nloc*K; Bb = X  + (size_t)m0*K;   }

  auto stage = [&](int buf, int k0) {
#pragma unroll
    for (int i = 0; i < 2; ++i) {
      int pA = (i<<8) + tid;           // granule slot 0..511 (128 rows x 4 gran)
      int r = pA >> 2, go = (pA & 3) ^ ((r >> 1) & 3);
      gll16(&As[buf][((i<<8) + (wv<<6))*8], Ab + (size_t)r*K + k0 + (go<<3));
      gll16(&Bs[buf][((i<<8) + (wv<<6))*8], Bb + (size_t)r*K + k0 + (go<<3));
    }
  };

  floatx4 acc[4][4] = {};
  stage(0, 0);
  int cur = 0;
  for (int it = 0; it < 32; ++it) {
    __syncthreads();                   // drains buf[cur] loads; prev compute done
    if (it < 31) stage(cur ^ 1, (it + 1) << 5);
    bhalf8 af[4], bfr[4];
#pragma unroll
    for (int rt = 0; rt < 4; ++rt) {
      int row = wm + rt*16 + l15;
      af[rt] = *(const bhalf8*)&As[cur][(row<<5) + ((quad ^ ((row>>1)&3))<<3)];
    }
#pragma unroll
    for (int ct = 0; ct < 4; ++ct) {
      int row = wn + ct*16 + l15;
      bfr[ct] = *(const bhalf8*)&Bs[cur][(row<<5) + ((quad ^ ((row>>1)&3))<<3)];
    }
#pragma unroll
    for (int rt = 0; rt < 4; ++rt)
#pragma unroll
      for (int ct = 0; ct < 4; ++ct)
        acc[rt][ct] = __builtin_amdgcn_mfma_f32_16x16x32_bf16(af[rt], bfr[ct], acc[rt][ct], 0, 0, 0);
    cur ^= 1;
  }

  if (kind < 2) {                        // Q or K: RoPE epilogue -> (B,H,T,DH)
    short* Cb = kind ? Kb : Qb;
    const int hh = (nloc + wn) >> 6;
#pragma unroll
    for (int rt = 0; rt < 4; ++rt)
#pragma unroll
      for (int r = 0; r < 4; ++r) {
        int n  = m0 + wm + rt*16 + quad*4 + r;
        int bb = n >> 11, t = n & (T_-1);
        size_t base = ((size_t)(bb*H_ + hh)*T_ + t)*DH_;
        float tf = (float)t;
#pragma unroll
        for (int ct = 0; ct < 2; ++ct) {
          int ii = ct*16 + l15;
          float ang = tf * exp2f((float)ii * (-0.4152410118609203f));
          float sn = __sinf(ang), cs = __cosf(ang);
          float xlo = acc[rt][ct][r], xhi = acc[rt][ct+2][r];
          Cb[base + ii]      = f2bf(xlo*cs - xhi*sn);
          Cb[base + ii + 32] = f2bf(xhi*cs + xlo*sn);
        }
      }
  } else {                               // V: rows=channels, cols=tokens -> V^T
#pragma unroll
    for (int rt = 0; rt < 4; ++rt)
#pragma unroll
      for (int r = 0; r < 4; ++r) {
        int o = nloc + wm + rt*16 + quad*4 + r;
#pragma unroll
        for (int ct = 0; ct < 4; ++ct) {
          int n  = m0 + wn + ct*16 + l15;
          int bb = n >> 11, t = n & (T_-1);
          Vt[(size_t)bb*(C_*T_) + (size_t)o*T_ + t] = f2bf(acc[rt][ct][r]);
        }
      }
  }
}

// Final projection, same single-barrier dbuf structure. LDS 24 KB.
__global__ __launch_bounds__(256) void gemm_out(
    const short* __restrict__ A, const short* __restrict__ Bm, float* __restrict__ Cf)
{
  __shared__ __align__(16) short As[2][128*32];   // 8 KB per buf
  __shared__ __align__(16) short Bs[2][64*32];    // 4 KB per buf
  const int tid = threadIdx.x, lane = tid & 63, wv = tid >> 6;
  const int l15 = lane & 15, quad = lane >> 4;
  const int n0 = blockIdx.x << 6;
  const int m0 = blockIdx.y << 7;

  const short* Ab = A  + (size_t)m0 * C_;
  const short* Bb = Bm + (size_t)n0 * C_;

  auto stage = [&](int buf, int k0) {
#pragma unroll
    for (int i = 0; i < 2; ++i) {
      int p = (i<<8) + tid, r = p >> 2, go = (p & 3) ^ ((r >> 1) & 3);
      gll16(&As[buf][((i<<8) + (wv<<6))*8], Ab + (size_t)r*C_ + k0 + (go<<3));
    }
    {
      int p = tid, r = p >> 2, go = (p & 3) ^ ((r >> 1) & 3);
      gll16(&Bs[buf][(wv<<6)*8], Bb + (size_t)r*C_ + k0 + (go<<3));
    }
  };

  floatx4 acc[2][4] = {};
  stage(0, 0);
  int cur = 0;
  for (int it = 0; it < 32; ++it) {
    __syncthreads();
    if (it < 31) stage(cur ^ 1, (it + 1) << 5);
    bhalf8 af[2], bfr[4];
#pragma unroll
    for (int rt = 0; rt < 2; ++rt) {
      int row = (wv<<5) + rt*16 + l15;
      af[rt] = *(const bhalf8*)&As[cur][(row<<5) + ((quad ^ ((row>>1)&3))<<3)];
    }
#pragma unroll
    for (int ct = 0; ct < 4; ++ct) {
      int row = ct*16 + l15;
      bfr[ct] = *(const bhalf8*)&Bs[cur][(row<<5) + ((quad ^ ((row>>1)&3))<<3)];
    }
#pragma unroll
    for (int rt = 0; rt < 2; ++rt)
#pragma unroll
      for (int ct = 0; ct < 4; ++ct)
        acc[rt][ct] = __builtin_amdgcn_mfma_f32_16x16x32_bf16(af[rt], bfr[ct], acc[rt][ct], 0, 0, 0);
    cur ^= 1;
  }

#pragma unroll
  for (int rt = 0; rt < 2; ++rt)
#pragma unroll
    for (int r = 0; r < 4; ++r) {
      int n = m0 + (wv<<5) + rt*16 + quad*4 + r;
#pragma unroll
      for (int ct = 0; ct < 4; ++ct)
        Cf[(size_t)n * C_ + n0 + ct*16 + l15] = acc[rt][ct][r];
    }
}

// K (B,H,T,DH) -> Kt (B,H,DH,T). Grid 1024 = bh*32 + token-chunk.
__global__ __launch_bounds__(256) void transpose_k(
    const short* __restrict__ Kb, short* __restrict__ Kt)
{
  __shared__ short tile[64*66];
  const int idx = blockIdx.x, bh = idx >> 5, tc = idx & 31;
  const int t0 = tc << 6;
  const short* src = Kb + ((size_t)bh*T_ + t0) * DH_;
  int row = threadIdx.x >> 2, c0 = (threadIdx.x & 3) << 4;
  *(int4*)&tile[row*66 + c0]     = *(const int4*)&src[row*64 + c0];
  *(int4*)&tile[row*66 + c0 + 8] = *(const int4*)&src[row*64 + c0 + 8];
  __syncthreads();
  short* dst = Kt + (size_t)bh*DH_*T_;
  int d = threadIdx.x >> 2, k0 = (threadIdx.x & 3) << 4;
  short tmp[16];
#pragma unroll
  for (int i = 0; i < 16; ++i) tmp[i] = tile[(k0 + i)*66 + d];
  *(int4*)&dst[(size_t)d*T_ + t0 + k0]     = *(const int4*)&tmp[0];
  *(int4*)&dst[(size_t)d*T_ + t0 + k0 + 8] = *(const int4*)&tmp[8];
}

// Per-segment state summaries. R9: 256 blocks = bh*8 + p (4 chunks each;
// was 128 blocks = 0.5/CU, half the machine idle), single-barrier dbuf.
__global__ __launch_bounds__(256) void seg_state(
    const short* __restrict__ Kt, const short* __restrict__ Vt,
    short* __restrict__ Pseg)
{
  __shared__ __align__(16) short Ks[2][64*64];   // K^T [d][tok], swizzled
  __shared__ __align__(16) short Vs[2][64*64];   // V^T [e][tok], swizzled
  const int tid = threadIdx.x, lane = tid & 63, wv = tid >> 6;
  const int l15 = lane & 15, quad = lane >> 4;
  const int wrow = wv << 4;
  const int bh = blockIdx.x >> 3, p = blockIdx.x & 7;
  const int h = bh & 15;
  const float log2g = log2f(1.f - exp2f(-5.f - (float)h));
  const float g64 = exp2f(log2g * 64.f);

  float wgt[16];
#pragma unroll
  for (int ks = 0; ks < 2; ++ks)
#pragma unroll
    for (int i = 0; i < 8; ++i)
      wgt[ks*8 + i] = exp2f(log2g * (float)(64 - (ks*32 + (quad<<3) + i)));

  const short* Ktg = Kt + (size_t)bh*DH_*T_;
  const short* Vtg = Vt + (size_t)bh*DH_*T_;

  auto stage = [&](int buf, int jc) {
    const int m0 = ((p<<2) + jc) << 6;
#pragma unroll
    for (int i = 0; i < 2; ++i) {
      int slot = (i<<8) + tid;
      int r = slot >> 3, g = (slot & 7) ^ (r & 7);
      gll16(&Ks[buf][((i<<8) + (wv<<6))*8], Ktg + (size_t)r*T_ + m0 + (g<<3));
      gll16(&Vs[buf][((i<<8) + (wv<<6))*8], Vtg + (size_t)r*T_ + m0 + (g<<3));
    }
  };

  floatx4 acc[4] = {};
  stage(0, 0);
  int cur = 0;
  for (int j = 0; j < 4; ++j) {
    __syncthreads();
    if (j < 3) stage(cur ^ 1, j + 1);
#pragma unroll
    for (int ct = 0; ct < 4; ++ct)
#pragma unroll
      for (int r = 0; r < 4; ++r) acc[ct][r] *= g64;
#pragma unroll
    for (int ks = 0; ks < 2; ++ks) {
      int row = wrow + l15;
      bhalf8 va = *(const bhalf8*)&Vs[cur][(row<<6) + ((((ks<<2)+quad) ^ (row&7))<<3)];
      bhalf8 aw;
#pragma unroll
      for (int i = 0; i < 8; ++i) aw[i] = f2bf(bf2f(va[i]) * wgt[ks*8 + i]);
      bhalf8 bk[4];
#pragma unroll
      for (int ct = 0; ct < 4; ++ct) {
        int kr = ct*16 + l15;
        bk[ct] = *(const bhalf8*)&Ks[cur][(kr<<6) + ((((ks<<2)+quad) ^ (kr&7))<<3)];
      }
#pragma unroll
      for (int ct = 0; ct < 4; ++ct)
        acc[ct] = __builtin_amdgcn_mfma_f32_16x16x32_bf16(aw, bk[ct], acc[ct], 0, 0, 0);
    }
    cur ^= 1;
  }
  size_t base = (size_t)(bh*8 + p) * 2 * 4096;
#pragma unroll
  for (int ct = 0; ct < 4; ++ct)
#pragma unroll
    for (int r = 0; r < 4; ++r) {
      int e = wrow + (quad<<2) + r, d = ct*16 + l15;
      float x = acc[ct][r];
      short hi = f2bf(x);
      short lo = f2bf(x - bf2f(hi));
      Pseg[base + e*64 + d]        = hi;
      Pseg[base + 4096 + e*64 + d] = lo;
    }
}

// Chunked retention: grid 1024 uniform blocks = (bh, chunk).
// R9: segments are 256 tokens (scan <=3 chunks, sum <=7 summaries).
__global__ __launch_bounds__(256) void retention_chunk(
    const short* __restrict__ Qb, const short* __restrict__ Kb,
    const short* __restrict__ Kt, const short* __restrict__ Vt,
    const short* __restrict__ Pseg,
    const float* __restrict__ gnw, const float* __restrict__ gnb,
    short* __restrict__ Xn)
{
  __shared__ __align__(16) short Vs[64*64];    // V^T [e][tok] (scan, then own)
  __shared__ __align__(16) short Kts[64*64];   // K^T [d][tok] (scan)
  __shared__ __align__(16) short KSs[64*64];   // K [tok][d], reused as Ss
  __shared__ __align__(16) short Sh[64*64];    // state hi [e][d]
  __shared__ __align__(16) short Sl[64*64];    // state lo [e][d]

  const int tid = threadIdx.x, lane = tid & 63, wv = tid >> 6;
  const int l15 = lane & 15, quad = lane >> 4;
  const int wrow = wv << 4;

  // idx -> (bh, c) with j varying among stride-256 siblings (CU balance)
  const int idx = blockIdx.x;
  const int bh = idx & 31;
  const int cc = idx >> 5;
  const int c  = ((cc & 7) << 2) | (cc >> 3);
  const int p = c >> 2, j = c & 3;
  const int b = bh >> 4, h = bh & 15;
  const int n0 = c << 6;

  const float log2g = log2f(1.f - exp2f(-5.f - (float)h));
  const float g64 = exp2f(log2g * 64.f);

  const short* Qg  = Qb + ((size_t)bh*T_ + n0 + wrow) * DH_;
  const short* Kg  = Kb + (size_t)bh*T_*DH_;
  const short* Ktg = Kt + (size_t)bh*DH_*T_;
  const short* Vtg = Vt + (size_t)bh*DH_*T_;

  bhalf8 aq[2];
#pragma unroll
  for (int ks = 0; ks < 2; ++ks)
    aq[ks] = *(const bhalf8*)(Qg + (size_t)l15*DH_ + ks*32 + quad*8);

  float rowf[4], colf0[4];
#pragma unroll
  for (int r = 0; r < 4; ++r)
    rowf[r] = exp2f(log2g * (float)(wrow + (quad<<2) + r)) * 0.125f;
#pragma unroll
  for (int ct = 0; ct < 4; ++ct)
    colf0[ct] = exp2f(-log2g * (float)(ct*16 + l15));

  const bool has_state = (c > 0);

  // ---- state scan over own-segment chunks 0..j-1 ----
  floatx4 st[4] = {};
  if (j > 0) {
    float wgt[16];
#pragma unroll
    for (int ks = 0; ks < 2; ++ks)
#pragma unroll
      for (int i = 0; i < 8; ++i)
        wgt[ks*8 + i] = exp2f(log2g * (float)(64 - (ks*32 + (quad<<3) + i)));
    for (int jp = 0; jp < j; ++jp) {
      if (log2g * (float)((j - 1 - jp) << 6) < -34.f) continue; // fully decayed
      const int m0 = ((p<<2) + jp) << 6;
      __syncthreads();
#pragma unroll
      for (int i = 0; i < 2; ++i) {
        int slot = (i<<8) + tid;
        int r = slot >> 3, g = (slot & 7) ^ (r & 7);
        gll16(&Kts[((i<<8) + (wv<<6))*8], Ktg + (size_t)r*T_ + m0 + (g<<3));
        gll16(&Vs[((i<<8) + (wv<<6))*8],  Vtg + (size_t)r*T_ + m0 + (g<<3));
      }
      __syncthreads();
#pragma unroll
      for (int ct = 0; ct < 4; ++ct)
#pragma unroll
        for (int r = 0; r < 4; ++r) st[ct][r] *= g64;
#pragma unroll
      for (int ks = 0; ks < 2; ++ks) {
        int row = wrow + l15;
        bhalf8 va = *(const bhalf8*)&Vs[(row<<6) + ((((ks<<2)+quad) ^ (row&7))<<3)];
        bhalf8 aw;
#pragma unroll
        for (int i = 0; i < 8; ++i) aw[i] = f2bf(bf2f(va[i]) * wgt[ks*8 + i]);
        bhalf8 bk[4];
#pragma unroll
        for (int ct = 0; ct < 4; ++ct) {
          int kr = ct*16 + l15;
          bk[ct] = *(const bhalf8*)&Kts[(kr<<6) + ((((ks<<2)+quad) ^ (kr&7))<<3)];
        }
#pragma unroll
        for (int ct = 0; ct < 4; ++ct)
          st[ct] = __builtin_amdgcn_mfma_f32_16x16x32_bf16(aw, bk[ct], st[ct], 0, 0, 0);
      }
    }
  }
  // ---- add weighted previous-segment summaries (256-token segments) ----
  for (int pp = 0; pp < p; ++pp) {
    float wexp = log2g * (float)(n0 - ((pp + 1) << 8));
    if (wexp < -34.f) continue;
    float w = exp2f(wexp);
    const short* Pg = Pseg + (size_t)(bh*8 + pp) * 2 * 4096;
#pragma unroll
    for (int ct = 0; ct < 4; ++ct)
#pragma unroll
      for (int r = 0; r < 4; ++r) {
        int e = wrow + (quad<<2) + r, d = ct*16 + l15;
        st[ct][r] += w * (bf2f(Pg[e*64 + d]) + bf2f(Pg[4096 + e*64 + d]));
      }
  }
  // ---- split state to bf16 hi/lo in LDS ----
  if (has_state) {
#pragma unroll
    for (int ct = 0; ct < 4; ++ct)
#pragma unroll
      for (int r = 0; r < 4; ++r) {
        int e = wrow + (quad<<2) + r, d = ct*16 + l15;
        float x = st[ct][r];
        short hi = f2bf(x);
        short lo = f2bf(x - bf2f(hi));
        int addr = (e<<6) + ((((d>>3) ^ (e&7))<<3)) + (d&7);
        Sh[addr] = hi; Sl[addr] = lo;
      }
  }

  // ---- stage own chunk: K token-major + V^T ----
  __syncthreads();                     // covers Sh/Sl writes + frees Vs/Kts
#pragma unroll
  for (int i = 0; i < 2; ++i) {
    int slot = (i<<8) + tid;
    int r = slot >> 3, g = (slot & 7) ^ (r & 7);
    gll16(&KSs[((i<<8) + (wv<<6))*8], Kg  + (size_t)(n0 + r)*DH_ + (g<<3));
    gll16(&Vs[((i<<8) + (wv<<6))*8],  Vtg + (size_t)r*T_ + n0 + (g<<3));
  }
  __syncthreads();

  // ---- intra: QK^T on diagonal chunk ----
  floatx4 sacc[4] = {};
#pragma unroll
  for (int ks = 0; ks < 2; ++ks) {
    bhalf8 bk[4];
#pragma unroll
    for (int ct = 0; ct < 4; ++ct) {
      int row = ct*16 + l15;
      bk[ct] = *(const bhalf8*)&KSs[(row<<6) + ((((ks<<2)+quad) ^ (row&7))<<3)];
    }
#pragma unroll
    for (int ct = 0; ct < 4; ++ct)
      sacc[ct] = __builtin_amdgcn_mfma_f32_16x16x32_bf16(aq[ks], bk[ct], sacc[ct], 0, 0, 0);
  }
  __syncthreads();                     // all waves done reading KSs -> reuse as Ss
#pragma unroll
  for (int ct = 0; ct < 4; ++ct) {
    float cf = colf0[ct];
    int colg = (ct<<1) + (l15>>3);
    int m = ct*16 + l15;
#pragma unroll
    for (int r = 0; r < 4; ++r) {
      int row = wrow + (quad<<2) + r;
      float v = (row >= m) ? sacc[ct][r] * (rowf[r] * cf) : 0.f;
      KSs[(row<<6) + ((colg ^ ((row>>1)&7))<<3) + (l15&7)] = f2bf(v);
    }
  }
  // no barrier: wave reads back only its own Ss rows
  floatx4 oacc[4] = {};
#pragma unroll
  for (int ks = 0; ks < 2; ++ks) {
    int row = wrow + l15;
    bhalf8 as_ = *(const bhalf8*)&KSs[(row<<6) + ((((ks<<2)+quad) ^ ((row>>1)&7))<<3)];
    bhalf8 bv[4];
#pragma unroll
    for (int ct = 0; ct < 4; ++ct) {
      int vrow = ct*16 + l15;
      bv[ct] = *(const bhalf8*)&Vs[(vrow<<6) + ((((ks<<2)+quad) ^ (vrow&7))<<3)];
    }
#pragma unroll
    for (int ct = 0; ct < 4; ++ct)
      oacc[ct] = __builtin_amdgcn_mfma_f32_16x16x32_bf16(as_, bv[ct], oacc[ct], 0, 0, 0);
  }

  // ---- inter: O += gamma^i/8 * Q @ St ----
  if (has_state) {
    floatx4 iacc[4] = {};
#pragma unroll
    for (int ks = 0; ks < 2; ++ks) {
      bhalf8 bhf[4], blf[4];
#pragma unroll
      for (int ct = 0; ct < 4; ++ct) {
        int er = ct*16 + l15;
        int ga = ((((ks<<2)+quad) ^ (er&7))<<3);
        bhf[ct] = *(const bhalf8*)&Sh[(er<<6) + ga];
        blf[ct] = *(const bhalf8*)&Sl[(er<<6) + ga];
      }
#pragma unroll
      for (int ct = 0; ct < 4; ++ct) {
        iacc[ct] = __builtin_amdgcn_mfma_f32_16x16x32_bf16(aq[ks], bhf[ct], iacc[ct], 0, 0, 0);
        iacc[ct] = __builtin_amdgcn_mfma_f32_16x16x32_bf16(aq[ks], blf[ct], iacc[ct], 0, 0, 0);
      }
    }
#pragma unroll
    for (int ct = 0; ct < 4; ++ct)
#pragma unroll
      for (int r = 0; r < 4; ++r)
        oacc[ct][r] += rowf[r] * iacc[ct][r];
  }

  // ---- fused GroupNorm over DH, write (B,T,C) bf16 ----
#pragma unroll
  for (int r = 0; r < 4; ++r) {
    float s1 = oacc[0][r] + oacc[1][r] + oacc[2][r] + oacc[3][r];
    float s2 = oacc[0][r]*oacc[0][r] + oacc[1][r]*oacc[1][r]
             + oacc[2][r]*oacc[2][r] + oacc[3][r]*oacc[3][r];
#pragma unroll
    for (int off = 1; off < 16; off <<= 1) {
      s1 += __shfl_xor(s1, off);
      s2 += __shfl_xor(s2, off);
    }
    float mean = s1 * (1.f/64.f);
    float var  = s2 * (1.f/64.f) - mean*mean;
    float rstd = rsqrtf(var + 1e-5f);
    int t = n0 + wrow + (quad<<2) + r;
    size_t obase = ((size_t)b*T_ + t)*C_ + h*DH_;
#pragma unroll
    for (int ct = 0; ct < 4; ++ct) {
      int d = ct*16 + l15;
      float y = (oacc[ct][r] - mean)*rstd*gnw[h*DH_ + d] + gnb[h*DH_ + d];
      Xn[obase + d] = f2bf(y);
    }
  }
}

extern "C" void kernel_launch(void* const* d_in, const int* in_sizes, int n_in,
                              void* d_out, int out_size, void* d_ws, size_t ws_size,
                              hipStream_t stream) {
  (void)in_sizes; (void)n_in; (void)out_size; (void)ws_size;
  const float* x   = (const float*)d_in[0];
  const float* Wq  = (const float*)d_in[1];
  const float* Wk  = (const float*)d_in[2];
  const float* Wv  = (const float*)d_in[3];
  const float* Wo  = (const float*)d_in[4];
  const float* gnw = (const float*)d_in[5];
  const float* gnb = (const float*)d_in[6];
  float* out = (float*)d_out;

  char* ws = (char*)d_ws;                 // 48 MB total
  short* Xb   = (short*)(ws);             // [0,8): x bf16; reused as Ktb after qkv
  short* Ktb  = (short*)(ws);             //   K^T (B,H,DH,T)
  short* Wqb  = (short*)(ws + (8u<<20));  // [8,12): Wq+Wk bf16; reused as Pseg (4 MB)
  short* Pseg = (short*)(ws + (8u<<20));  //   segment states, 32*8*2*4096 shorts
  short* Wkb  = (short*)(ws + (10u<<20));
  short* Wvb  = (short*)(ws + (12u<<20));
  short* Wob  = (short*)(ws + (14u<<20));
  short* Qb   = (short*)(ws + (16u<<20)); // (B,H,T,DH)
  short* Kb   = (short*)(ws + (24u<<20)); // (B,H,T,DH)
  short* Vtw  = (short*)(ws + (32u<<20)); // V^T (B,H,DH,T)
  short* Xn   = (short*)(ws + (40u<<20)); // retention out (B,T,C) bf16

  cvt_all<<<(M_*C_/4 + 4*(C_*C_/4)) / 256, 256, 0, stream>>>(
      x, Wq, Wk, Wv, Wo, Xb, Wqb, Wkb, Wvb, Wob);

  gemm_qkv<<<dim3(24, 32), 256, 0, stream>>>(Xb, Wqb, Wkb, Wvb, Qb, Kb, Vtw);
  transpose_k<<<1024, 256, 0, stream>>>(Kb, Ktb);
  seg_state<<<256, 256, 0, stream>>>(Ktb, Vtw, Pseg);
  retention_chunk<<<1024, 256, 0, stream>>>(Qb, Kb, Ktb, Vtw, Pseg, gnw, gnb, Xn);
  gemm_out<<<dim3(16, 32), 256, 0, stream>>>(Xn, Wob, out);
}